// Round 15
// baseline (1558.313 us; speedup 1.0000x reference)
//
#include <hip/hip_runtime.h>
#include <stdint.h>

#define DMD 512
#define NSEQ 512
#define NBATCH 4
#define WROWS 32768
#define VOCAB 32000

#define OFF_HALT   65536000L
#define OFF_Q      65536004L
#define OFF_STEPS  66584580L
#define OFF_HALTED 66584584L

typedef __attribute__((ext_vector_type(8))) short short8v;
typedef __attribute__((ext_vector_type(4))) float f32x4;

__device__ __forceinline__ ushort f2bf(float f){
  uint u = __builtin_bit_cast(uint, f);
  u += 0x7fffu + ((u >> 16) & 1u);
  return (ushort)(u >> 16);
}
__device__ __forceinline__ float bf2f(ushort h){
  return __builtin_bit_cast(float, (uint)h << 16);
}

// ---------------- reductions ----------------
__device__ __forceinline__ float block_reduce_sum256(float v, float* red){
  int t = threadIdx.x;
  red[t] = v; __syncthreads();
  for (int o = 128; o; o >>= 1){
    if (t < o) red[t] += red[t+o];
    __syncthreads();
  }
  float r = red[0]; __syncthreads();
  return r;
}

// ============ mega-fused LayerNorm ============
template<int MODE, int TR, int QP, int HALT>
__global__ __launch_bounds__(512) void k_ln1(
    const float* in, float* QaW, const float* X,
    const int* halted32, const float* ih, const float* ch,
    ushort* __restrict__ outb, ushort* __restrict__ outT,
    float* __restrict__ qp_part,
    const float* __restrict__ g, const float* __restrict__ b,
    const float* __restrict__ hW, float* __restrict__ hpart)
{
  __shared__ ushort lt[TR ? 16 : 1][TR ? 520 : 1];
  __shared__ float red[QP ? 4096 : 1];
  const int bb = blockIdx.y, rg = blockIdx.x;
  const int n0 = rg*16;
  const int tid = threadIdx.x, wave = tid >> 6, lane = tid & 63;
  const int c8 = lane*8;
  float qacc[8] = {};
  #pragma unroll
  for (int rr = 0; rr < 2; rr++){
    const int n = n0 + wave*2 + rr;
    const long rowo = (long)bb*262144 + (long)n*512;
    float x[8];
    if (MODE == 1){
      bool hall = (halted32[0] != 0);
      #pragma unroll
      for (int i = 0; i < 8; i++){
        float base = hall ? ih[c8+i] : ch[rowo + c8 + i];
        x[i] = base + X[rowo + c8 + i];
      }
      #pragma unroll
      for (int i = 0; i < 8; i++) QaW[rowo + c8 + i] = x[i];
    } else if (MODE == 2){
      #pragma unroll
      for (int i = 0; i < 8; i++) x[i] = in[rowo + c8 + i] + X[rowo + c8 + i];
      #pragma unroll
      for (int i = 0; i < 8; i++) QaW[rowo + c8 + i] = x[i];
    } else {
      float4 a0 = *(const float4*)(in + rowo + c8);
      float4 a1 = *(const float4*)(in + rowo + c8 + 4);
      x[0]=a0.x; x[1]=a0.y; x[2]=a0.z; x[3]=a0.w;
      x[4]=a1.x; x[5]=a1.y; x[6]=a1.z; x[7]=a1.w;
    }
    float s = 0.f, sq = 0.f;
    #pragma unroll
    for (int i = 0; i < 8; i++){ s += x[i]; sq += x[i]*x[i]; }
    #pragma unroll
    for (int m = 32; m; m >>= 1){
      s  += __shfl_xor(s, m);
      sq += __shfl_xor(sq, m);
    }
    float mu = s*(1.f/512.f);
    float var = sq*(1.f/512.f) - mu*mu;
    float rs = rsqrtf(var + 1e-5f);
    float hd = 0.f;
    short8v ov;
    #pragma unroll
    for (int i = 0; i < 8; i++){
      float o = (x[i]-mu)*rs*g[c8+i] + b[c8+i];
      ov[i] = (short)f2bf(o);
      if (QP) qacc[i] += o;
      if (HALT) hd += o * hW[c8+i];
    }
    *(short8v*)&outb[rowo + c8] = ov;
    if (TR) *(short8v*)&lt[n & 15][c8] = ov;
    if (HALT){
      #pragma unroll
      for (int m = 32; m; m >>= 1) hd += __shfl_xor(hd, m);
      if (lane == 0) atomicAdd(&hpart[bb], hd);
    }
  }
  if (QP){
    #pragma unroll
    for (int i = 0; i < 8; i++) red[wave*512 + c8 + i] = qacc[i];
    __syncthreads();
    if (wave == 0){
      #pragma unroll
      for (int i = 0; i < 8; i++){
        int c = c8 + i;
        float s = 0.f;
        #pragma unroll
        for (int w = 0; w < 8; w++) s += red[w*512 + c];
        qp_part[((long)bb*32 + rg)*512 + c] = s;
      }
    }
  }
  if (TR){
    __syncthreads();
    #pragma unroll 4
    for (int p = 0; p < 16; p++){
      int d = p*32 + (tid >> 4);
      int n = tid & 15;
      outT[(long)bb*262144 + (long)d*512 + n0 + n] = lt[n][d];
    }
  }
}

// embed + pos + LN fused -> X
__global__ void k_embed_ln(const int* __restrict__ inputs, const int* __restrict__ cinputs,
                           const int* __restrict__ halted32,
                           const float* __restrict__ emb, const float* __restrict__ pos,
                           const float* __restrict__ g, const float* __restrict__ b,
                           float* __restrict__ X){
  __shared__ float red[256];
  int r = blockIdx.x; int t = threadIdx.x;
  int n = r & 511;
  bool hall = (halted32[0] != 0);
  int tok = hall ? inputs[r] : cinputs[r];
  const float* e = emb + (long)tok*DMD;
  const float* p = pos + (long)n*DMD;
  float v0 = e[t]+p[t], v1 = e[t+256]+p[t+256];
  float mu = block_reduce_sum256(v0+v1, red) * (1.f/DMD);
  float d0 = v0-mu, d1 = v1-mu;
  float var = block_reduce_sum256(d0*d0+d1*d1, red) * (1.f/DMD);
  float rs = rsqrtf(var + 1e-5f);
  X[(long)r*DMD+t]     = d0*rs*g[t]     + b[t];
  X[(long)r*DMD+t+256] = d1*rs*g[t+256] + b[t+256];
}

// ---------------- spectral norm v-pass + LINEAR bf16 W copy ---------------
__global__ __launch_bounds__(512) void k_sn_v(
    const float* __restrict__ hqW, const float* __restrict__ hkW,
    const float* __restrict__ uq, const float* __restrict__ uk,
    float* __restrict__ vpart, ushort* __restrict__ Wbf){
  __shared__ float red[8*520];
  int z = blockIdx.y; int k = z >> 1, qk = z & 1;
  const float* W = (qk ? hkW : hqW) + (long)k*WROWS*DMD;
  const float* u = (qk ? uk : uq) + (long)k*WROWS;
  ushort* Wb = Wbf ? (Wbf + (long)z*WROWS*DMD) : nullptr;
  int t = threadIdx.x;
  int c8 = (t & 63) * 8;
  int rsub = t >> 6;
  int r0 = blockIdx.x * 256;
  float acc[8] = {};
  for (int r = rsub; r < 256; r += 16){
    int ra = r0 + r, rb = r0 + r + 8;
    long offa = (long)ra*DMD + c8, offb = (long)rb*DMD + c8;
    f32x4 a0 = __builtin_nontemporal_load((const f32x4*)(W + offa));
    f32x4 a1 = __builtin_nontemporal_load((const f32x4*)(W + offa + 4));
    f32x4 b0 = __builtin_nontemporal_load((const f32x4*)(W + offb));
    f32x4 b1 = __builtin_nontemporal_load((const f32x4*)(W + offb + 4));
    float ua = u[ra], ub = u[rb];
    float av[8] = {a0[0],a0[1],a0[2],a0[3],a1[0],a1[1],a1[2],a1[3]};
    float bv[8] = {b0[0],b0[1],b0[2],b0[3],b1[0],b1[1],b1[2],b1[3]};
    #pragma unroll
    for (int i = 0; i < 8; i++) acc[i] += av[i]*ua + bv[i]*ub;
    if (Wb){
      short8v oa, ob;
      #pragma unroll
      for (int i = 0; i < 8; i++){ oa[i] = (short)f2bf(av[i]); ob[i] = (short)f2bf(bv[i]); }
      __builtin_nontemporal_store(oa, (short8v*)(Wb + offa));
      __builtin_nontemporal_store(ob, (short8v*)(Wb + offb));
    }
  }
  #pragma unroll
  for (int i = 0; i < 8; i++) red[rsub*520 + c8 + i] = acc[i];
  __syncthreads();
  if (rsub == 0){
    #pragma unroll
    for (int i = 0; i < 8; i++){
      int c = c8 + i;
      float s = 0.f;
      #pragma unroll
      for (int w = 0; w < 8; w++) s += red[w*520 + c];
      vpart[((long)z*128 + blockIdx.x)*512 + c] = s;
    }
  }
}

// reduce vpart -> normalized v; write qpb row4 = v-hat, zero rows 5..63
__global__ __launch_bounds__(512) void k_sn_norm(const float* __restrict__ vpart,
                                                 float* __restrict__ vraw,
                                                 ushort* __restrict__ qpb){
  __shared__ float red[512];
  int z = blockIdx.x; int t = threadIdx.x;
  float s = 0.f;
  for (int c = 0; c < 128; c++) s += vpart[((long)z*128 + c)*512 + t];
  red[t] = s*s; __syncthreads();
  for (int o = 256; o; o >>= 1){
    if (t < o) red[t] += red[t+o];
    __syncthreads();
  }
  float nrm = sqrtf(red[0]);
  float v = s / (nrm + 1e-12f);
  vraw[z*512 + t] = v;
  ushort* p = qpb + (long)z*32768;
  p[4*512 + t] = f2bf(v);
  for (int r = 5; r < 64; r++) p[r*512 + t] = 0;
}

// f32 fallback sigma pass
__global__ void k_sn_s(const float* __restrict__ hqW, const float* __restrict__ hkW,
                       const float* __restrict__ vraw, float* __restrict__ ssqp){
  int z = blockIdx.y; int k = z >> 1, qk = z & 1;
  const float* W = (qk ? hkW : hqW) + (long)k*WROWS*DMD;
  const float* v = vraw + z*DMD;
  int wave = threadIdx.x >> 6, lane = threadIdx.x & 63;
  float vreg[8];
  #pragma unroll
  for (int i = 0; i < 8; i++) vreg[i] = v[lane + 64*i];
  int r0 = blockIdx.x*256 + wave*64;
  float acc = 0.f;
  for (int r = r0; r < r0+64; r++){
    float p = 0.f;
    #pragma unroll
    for (int i = 0; i < 8; i++)
      p += W[(long)r*DMD + lane + 64*i] * vreg[i];
    for (int off = 32; off; off >>= 1) p += __shfl_down(p, off);
    if (lane == 0) acc += p*p;
  }
  if (lane == 0) atomicAdd(&ssqp[z*64 + (blockIdx.x & 63)], acc);
}

// f32 fallback proj
__global__ void k_proj(const float* __restrict__ hqW, const float* __restrict__ hkW,
                       const float* __restrict__ qp,
                       ushort* __restrict__ OqT, ushort* __restrict__ OkT, int k){
  int z = blockIdx.y;
  const float* W = (z ? hkW : hqW) + (long)k*WROWS*DMD;
  ushort* O = z ? OkT : OqT;
  int wave = threadIdx.x >> 6, lane = threadIdx.x & 63;
  long r = (long)blockIdx.x*4 + wave;
  float a0=0,a1=0,a2=0,a3=0;
  for (int j = lane; j < DMD; j += 64){
    float w = W[r*DMD + j];
    a0 += w*qp[j]; a1 += w*qp[DMD+j]; a2 += w*qp[2*DMD+j]; a3 += w*qp[3*DMD+j];
  }
  for (int off = 32; off; off >>= 1){
    a0 += __shfl_down(a0,off); a1 += __shfl_down(a1,off);
    a2 += __shfl_down(a2,off); a3 += __shfl_down(a3,off);
  }
  if (lane == 0){
    int d = (int)(r >> 6), e = (int)(r & 63);
    long o = (long)e*512 + d;
    O[o] = f2bf(a0); O[32768+o] = f2bf(a1);
    O[2*32768+o] = f2bf(a2); O[3*32768+o] = f2bf(a3);
  }
}

// ---------------- bf16 MFMA GEMM: C = A . B^T (+epilogue), BK=64 ----------
// EPI: 0 none | 1 elu(acc*invsigma+bias[col])+1 | 3 res+sp*(acc+bias[col])
//      | 4 acc+res (+aux store) | 6 proj (rows<4 bf16; row4 -> ssq atomic)
// CVTB: B operand is f32 global, converted during staging (NT loads).
// TRN: tm from blockIdx.x, tn from blockIdx.y (B-panel L2 reuse).
// PERM: B tile row p gathers original row (p&511)*64 + (p>>9).
// NTC: non-temporal C stores (touch-once output, don't evict B from LLC).
template<int BM, int BN, int WM, int WN, int EPI, int BFOUT, int DUAL, int RSUM,
         int CVTB = 0, int TRN = 0, int PERM = 0, int NTC = 0>
__global__ __launch_bounds__(256) void mm_bt(
    const ushort* __restrict__ A, const ushort* __restrict__ B, void* __restrict__ C,
    int N, int K, long sA, long sB, long sC,
    const float* __restrict__ bias, const float* __restrict__ bias2,
    const float* __restrict__ res, const ushort* __restrict__ resb,
    const float* __restrict__ dtp, int dtidx,
    float* __restrict__ aux, const float* __restrict__ ssqp)
{
  __shared__ ushort As[BM*64];
  __shared__ ushort Bs[BN*64];
  const int z = blockIdx.z;
  const float* biasz = bias;
  if (DUAL){
    A += (long)(z & 3)*sA;
    if (z >= 4) biasz = bias2;
  } else {
    A += (long)z*sA;
  }
  if (!CVTB) B += (long)z*sB;
  const int tm = (TRN ? blockIdx.x : blockIdx.y)*BM;
  const int tn = DUAL ? 0 : (TRN ? blockIdx.y : blockIdx.x)*BN;
  const int tid = threadIdx.x;
  const int wid = tid >> 6, lane = tid & 63;
  constexpr int NWN = BN/WN;
  const int wr = wid / NWN, wc = wid % NWN;
  constexpr int FM = WM/16, FN = WN/16;
  const int ln15 = lane & 15, kq = lane >> 4;
  constexpr int LA = BM/32;
  constexpr int LB = BN/32;
  f32x4 acc[FM][FN] = {};

  for (int k0 = 0; k0 < K; k0 += 64){
    #pragma unroll
    for (int l = 0; l < LA; l++){
      int slot = tid + l*256;
      int row = slot >> 3, ch = slot & 7;
      int gch = ch ^ (row & 7);
      const char* g = (const char*)(A + (long)(tm+row)*K + k0) + gch*16;
      ushort* lp = As + (size_t)(wid*64 + l*256)*8;
      __builtin_amdgcn_global_load_lds((const __attribute__((address_space(1))) void*)g,
                                       (__attribute__((address_space(3))) void*)lp, 16, 0, 0);
    }
    #pragma unroll
    for (int l = 0; l < LB; l++){
      int slot = tid + l*256;
      int row = slot >> 3, ch = slot & 7;
      int gch = ch ^ (row & 7);
      if (CVTB){
        const float* Bf = (const float*)B;
        const float* src = Bf + (long)(tn+row)*K + k0 + gch*8;
        f32x4 v0 = __builtin_nontemporal_load((const f32x4*)src);
        f32x4 v1 = __builtin_nontemporal_load((const f32x4*)(src + 4));
        float vv[8] = {v0[0],v0[1],v0[2],v0[3],v1[0],v1[1],v1[2],v1[3]};
        short8v o;
        #pragma unroll
        for (int i = 0; i < 8; i++) o[i] = (short)f2bf(vv[i]);
        *(short8v*)&Bs[(size_t)slot*8] = o;
      } else {
        long brow;
        if (PERM){
          int p = tn + row;
          brow = (long)((p & 511)*64 + (p >> 9));
        } else {
          brow = (long)(tn + row);
        }
        const char* g = (const char*)(B + brow*K + k0) + gch*16;
        ushort* lp = Bs + (size_t)(wid*64 + l*256)*8;
        __builtin_amdgcn_global_load_lds((const __attribute__((address_space(1))) void*)g,
                                         (__attribute__((address_space(3))) void*)lp, 16, 0, 0);
      }
    }
    __syncthreads();
    #pragma unroll
    for (int ks = 0; ks < 2; ks++){
      short8v af[FM], bfr[FN];
      #pragma unroll
      for (int i = 0; i < FM; i++){
        int row = wr*WM + i*16 + ln15;
        af[i] = *(const short8v*)&As[row*64 + (((ks*4+kq) ^ (row&7))*8)];
      }
      #pragma unroll
      for (int j = 0; j < FN; j++){
        int row = wc*WN + j*16 + ln15;
        bfr[j] = *(const short8v*)&Bs[row*64 + (((ks*4+kq) ^ (row&7))*8)];
      }
      #pragma unroll
      for (int i = 0; i < FM; i++)
        #pragma unroll
        for (int j = 0; j < FN; j++)
          acc[i][j] = __builtin_amdgcn_mfma_f32_16x16x32_bf16(af[i], bfr[j], acc[i][j], 0, 0, 0);
    }
    __syncthreads();
  }

  float sp = 0.f, invs = 1.f;
  if (EPI == 3) sp = log1pf(expf(dtp[dtidx]));
  if (EPI == 1){
    const float* sq = ssqp + (DUAL ? (z >> 2)*64 : 0);
    float s2 = 0.f;
    for (int i = 0; i < 64; i++) s2 += sq[i];
    invs = (sqrtf(s2) + 1e-12f) / s2;
  }
  float* Cf = (float*)C + (long)z*sC;
  ushort* Cb = (ushort*)C + (long)z*sC;
  const float* rz = res ? (res + (long)z*sC) : nullptr;
  float sacc = 0.f;
  #pragma unroll
  for (int i = 0; i < FM; i++){
    int row0 = tm + wr*WM + i*16 + kq*4;
    #pragma unroll
    for (int j = 0; j < FN; j++){
      int col = tn + wc*WN + j*16 + ln15;
      #pragma unroll
      for (int r = 0; r < 4; r++){
        int row = row0 + r;
        long idx = (long)row*N + col;
        float v = acc[i][j][r];
        if (EPI == 6){
          if (row < 4) Cb[idx] = f2bf(v);
          else if (row == 4) sacc += v*v;
          continue;
        }
        if (EPI == 1){ v = v*invs + biasz[col]; v = v > 0.f ? v : expm1f(v); v += 1.f; }
        else if (EPI == 3){ v = rz[idx] + sp*(v + biasz[col]); }
        else if (EPI == 4){ v = v + rz[idx]; if (aux) aux[idx] = v; }
        if (BFOUT) Cb[idx] = f2bf(v);
        else if (NTC) __builtin_nontemporal_store(v, &Cf[idx]);
        else       Cf[idx] = v;
      }
    }
  }
  if (EPI == 6 && aux){
    sacc += __shfl_xor(sacc, 1); sacc += __shfl_xor(sacc, 2);
    sacc += __shfl_xor(sacc, 4); sacc += __shfl_xor(sacc, 8);
    if (wr == 0 && kq == 1 && ln15 == 0)
      atomicAdd(&aux[(long)z*64 + ((int)blockIdx.x & 63)], sacc);
  }
}

// ---------------- fused attention: S=Pq.Pk^T -> relu^2 -> rowsum + @Qn ----
__global__ __launch_bounds__(256) void k_attn(
    const ushort* __restrict__ Pqk, const ushort* __restrict__ QnT,
    const ushort* __restrict__ Qn, ushort* __restrict__ m_out)
{
  __shared__ ushort Aq[64*64];
  __shared__ ushort Bk[64*64];
  __shared__ ushort Qs[64*64];
  __shared__ ushort Ws[64*72];
  __shared__ float nrmL[2][64];
  const int cg = blockIdx.x, nt = blockIdx.y, b = blockIdx.z;
  const int tid = threadIdx.x, wid = tid >> 6;
  const int lane = tid & 63, ln15 = lane & 15, kq = lane >> 4;
  const int wr = wid >> 1, wc = wid & 1;
  const ushort* Pq  = Pqk + (long)b*32768 + (long)nt*4096;
  const ushort* Pk0 = Pqk + 131072 + (long)b*32768;
  const ushort* Qt  = QnT + (long)b*262144 + (long)(cg*64)*512;

  #pragma unroll
  for (int l = 0; l < 2; l++){
    int slot = tid + l*256;
    int row = slot >> 3, gch = (slot & 7) ^ (row & 7);
    __builtin_amdgcn_global_load_lds(
        (const __attribute__((address_space(1))) void*)((const char*)(Pq + (long)row*64) + gch*16),
        (__attribute__((address_space(3))) void*)(Aq + (size_t)(wid*64 + l*256)*8), 16, 0, 0);
  }
  f32x4 acc[2][2] = {};
  float nacc[2][4] = {};
  for (int mt = 0; mt < 8; mt++){
    #pragma unroll
    for (int l = 0; l < 2; l++){
      int slot = tid + l*256;
      int row = slot >> 3, gch = (slot & 7) ^ (row & 7);
      __builtin_amdgcn_global_load_lds(
          (const __attribute__((address_space(1))) void*)((const char*)(Pk0 + (long)mt*4096 + (long)row*64) + gch*16),
          (__attribute__((address_space(3))) void*)(Bk + (size_t)(wid*64 + l*256)*8), 16, 0, 0);
      __builtin_amdgcn_global_load_lds(
          (const __attribute__((address_space(1))) void*)((const char*)(Qt + (long)row*512 + mt*64) + gch*16),
          (__attribute__((address_space(3))) void*)(Qs + (size_t)(wid*64 + l*256)*8), 16, 0, 0);
    }
    __syncthreads();
    f32x4 sA[2][2] = {};
    #pragma unroll
    for (int ks = 0; ks < 2; ks++){
      short8v af[2], bfr[2];
      #pragma unroll
      for (int i = 0; i < 2; i++){
        int row = wr*32 + i*16 + ln15;
        af[i] = *(const short8v*)&Aq[row*64 + (((ks*4+kq) ^ (row&7))*8)];
      }
      #pragma unroll
      for (int j = 0; j < 2; j++){
        int row = wc*32 + j*16 + ln15;
        bfr[j] = *(const short8v*)&Bk[row*64 + (((ks*4+kq) ^ (row&7))*8)];
      }
      #pragma unroll
      for (int i = 0; i < 2; i++)
        #pragma unroll
        for (int j = 0; j < 2; j++)
          sA[i][j] = __builtin_amdgcn_mfma_f32_16x16x32_bf16(af[i], bfr[j], sA[i][j], 0, 0, 0);
    }
    float t[2][4] = {};
    #pragma unroll
    for (int i = 0; i < 2; i++)
      #pragma unroll
      for (int j = 0; j < 2; j++)
        #pragma unroll
        for (int r = 0; r < 4; r++){
          float v = fmaxf(sA[i][j][r], 0.f); v = v*v;
          t[i][r] += v;
          int row = wr*32 + i*16 + kq*4 + r;
          int col = wc*32 + j*16 + ln15;
          Ws[row*72 + col] = f2bf(v);
        }
    #pragma unroll
    for (int i = 0; i < 2; i++)
      #pragma unroll
      for (int r = 0; r < 4; r++){
        float x = t[i][r];
        x += __shfl_xor(x, 1); x += __shfl_xor(x, 2);
        x += __shfl_xor(x, 4); x += __shfl_xor(x, 8);
        nacc[i][r] += x;
      }
    __syncthreads();
    #pragma unroll
    for (int ks = 0; ks < 2; ks++){
      short8v af[2], bfr[2];
      #pragma unroll
      for (int i = 0; i < 2; i++){
        int row = wr*32 + i*16 + ln15;
        af[i] = *(const short8v*)&Ws[row*72 + (ks*4+kq)*8];
      }
      #pragma unroll
      for (int j = 0; j < 2; j++){
        int row = wc*32 + j*16 + ln15;
        bfr[j] = *(const short8v*)&Qs[row*64 + (((ks*4+kq) ^ (row&7))*8)];
      }
      #pragma unroll
      for (int i = 0; i < 2; i++)
        #pragma unroll
        for (int j = 0; j < 2; j++)
          acc[i][j] = __builtin_amdgcn_mfma_f32_16x16x32_bf16(af[i], bfr[j], acc[i][j], 0, 0, 0);
    }
    __syncthreads();
  }
  if (ln15 == 0){
    #pragma unroll
    for (int i = 0; i < 2; i++)
      #pragma unroll
      for (int r = 0; r < 4; r++)
        nrmL[wc][wr*32 + i*16 + kq*4 + r] = nacc[i][r];
  }
  __syncthreads();
  #pragma unroll
  for (int i = 0; i < 2; i++){
    #pragma unroll
    for (int r = 0; r < 4; r++){
      int rowl = wr*32 + i*16 + kq*4 + r;
      float Nr = fabsf(nrmL[0][rowl] + nrmL[1][rowl]) + 1.f;
      int n = nt*64 + rowl;
      #pragma unroll
      for (int j = 0; j < 2; j++){
        int col = cg*64 + wc*32 + j*16 + ln15;
        long idx = (long)b*262144 + (long)n*512 + col;
        m_out[idx] = f2bf(acc[i][j][r]/Nr - bf2f(Qn[idx]));
      }
    }
  }
}

// ---------------- small kernels ----------------
__global__ void k_qp2(const float* __restrict__ part, float* __restrict__ qp,
                      ushort* __restrict__ qpb){
  int b = blockIdx.x, t = threadIdx.x;
  float s = 0.f;
  #pragma unroll
  for (int c = 0; c < 32; c++) s += part[((long)b*32 + c)*512 + t];
  float val = s * (1.f/512.f);
  qp[b*512 + t] = val;
  ushort bv = f2bf(val);
  #pragma unroll
  for (int z = 0; z < 8; z++)
    qpb[(long)z*32768 + (long)b*512 + t] = bv;
}

__global__ void k_convfuse(const ushort* __restrict__ GU, const float* __restrict__ w,
                           ushort* __restrict__ Hc){
  int r = blockIdx.x;
  int n = r & 511;
  int c = threadIdx.x * 8;
  long base = (long)r*4096 + c;
  float o[8] = {};
  if (n > 0){
    short8v gv = *(const short8v*)&GU[base-4096];
    short8v uv = *(const short8v*)&GU[base-4096+2048];
    #pragma unroll
    for (int i = 0; i < 8; i++){
      float g = bf2f((ushort)gv[i]), u = bf2f((ushort)uv[i]);
      o[i] += g/(1.f+expf(-g))*u * w[(c+i)*3+0];
    }
  }
  {
    short8v gv = *(const short8v*)&GU[base];
    short8v uv = *(const short8v*)&GU[base+2048];
    #pragma unroll
    for (int i = 0; i < 8; i++){
      float g = bf2f((ushort)gv[i]), u = bf2f((ushort)uv[i]);
      o[i] += g/(1.f+expf(-g))*u * w[(c+i)*3+1];
    }
  }
  if (n < 511){
    short8v gv = *(const short8v*)&GU[base+4096];
    short8v uv = *(const short8v*)&GU[base+4096+2048];
    #pragma unroll
    for (int i = 0; i < 8; i++){
      float g = bf2f((ushort)gv[i]), u = bf2f((ushort)uv[i]);
      o[i] += g/(1.f+expf(-g))*u * w[(c+i)*3+2];
    }
  }
  short8v ov;
  #pragma unroll
  for (int i = 0; i < 8; i++) ov[i] = (short)f2bf(o[i]);
  *(short8v*)&Hc[(long)r*2048 + c] = ov;
}

__global__ void k_cvt3(const float* __restrict__ s0, ushort* __restrict__ d0, long n0,
                       const float* __restrict__ s1, ushort* __restrict__ d1, long n1,
                       const float* __restrict__ s2, ushort* __restrict__ d2, long n2){
  long i = ((long)blockIdx.x*256 + threadIdx.x)*4;
  const float* s; ushort* d; long off;
  if (i < n0){ s = s0; d = d0; off = i; }
  else if (i < n0 + n1){ s = s1; d = d1; off = i - n0; }
  else { s = s2; d = d2; off = i - n0 - n1; }
  float4 v = *(const float4*)(s + off);
  ushort4 o;
  o.x = f2bf(v.x); o.y = f2bf(v.y); o.z = f2bf(v.z); o.w = f2bf(v.w);
  *(ushort4*)(d + off) = o;
}

__global__ void k_fin(const int* __restrict__ halted32, const int* __restrict__ steps,
                      const float* __restrict__ hpart, const float* __restrict__ hb,
                      float* __restrict__ o_halt, float* __restrict__ o_steps,
                      float* __restrict__ o_halted){
  int t = threadIdx.x;
  if (t < NBATCH){
    o_halt[t] = hpart[t]*(1.f/512.f) + hb[0];
    bool hall = (halted32[0] != 0);
    int ns = (hall ? 0 : steps[t]) + 1;
    o_steps[t] = (float)ns;
    o_halted[t] = ns >= 6 ? 1.f : 0.f;
  }
}

// ---------------- launch ----------------
extern "C" void kernel_launch(void* const* d_in, const int* in_sizes, int n_in,
                              void* d_out, int out_size, void* d_ws, size_t ws_size,
                              hipStream_t stream)
{
  const int*     inputs       = (const int*)d_in[0];
  const int*     halted32     = (const int*)d_in[2];
  const int*     steps        = (const int*)d_in[3];
  const float*   carry_hidden = (const float*)d_in[4];
  const int*     carry_inputs = (const int*)d_in[5];
  const float*   embedding    = (const float*)d_in[7];
  const float*   pos_emb      = (const float*)d_in[8];
  const float*   in_g = (const float*)d_in[9];
  const float*   in_b = (const float*)d_in[10];
  const float*   init_hidden = (const float*)d_in[11];
  const float*   dt   = (const float*)d_in[12];
  const float*   mW   = (const float*)d_in[13];
  const float*   mb   = (const float*)d_in[14];
  const float*   hqW  = (const float*)d_in[15];
  const float*   hkW  = (const float*)d_in[16];
  const float*   uq   = (const float*)d_in[17];
  const float*   uk   = (const float*)d_in[18];
  const float*   BQb  = (const float*)d_in[19];
  const float*   BKb  = (const float*)d_in[20];
  const float*   g1   = (const float*)d_in[21];
  const float*   b1   = (const float*)d_in[22];
  const float*   g2   = (const float*)d_in[23];
  const float*   b2   = (const float*)d_in[24];
  const float*   WupW = (const float*)d_in[25];
  const float*   convW= (const float*)d_in[26];
  const float*   WdownW=(const float*)d_in[27];
  const float*   fin_g= (const float*)d_in[28];
  const float*   fin_b= (const float*)d_in[29];
  const float*   halt_W=(const float*)d_in[30];
  const float*   halt_b=(const float*)d_in[31];
  const float*   lm_head=(const float*)d_in[32];
  float* out = (float*)d_out;

  float* ws = (float*)d_ws;
  float*  X    = ws;
  float*  Qa   = ws +  1048576;
  float*  Qb   = ws +  2097152;
  ushort* qpb  = (ushort*)(ws + 3145728);      // 8 x 64 x 512 bf16
  float*  vpart  = ws + 3276800;               // 8 x 128 x 512 f32 (prologue only)
  float*  qp_part= ws + 3801088;               // 4 x 32 x 512 f32
  ushort* GU_bf  = (ushort*)(ws +  4194304);   // 8,388,608 elems
  ushort* Hc_bf  = (ushort*)(ws +  8388608);   // 4,194,304 elems
  ushort* m_bf   = (ushort*)(ws + 10485760);   // 1,048,576 elems
  ushort* QnT_bf = (ushort*)(ws + 11534336);   // 1,048,576 elems
  ushort* Pq_bf  = (ushort*)(ws + 12058624);   // 131,072 (Pk contiguous after)
  ushort* OqT    = (ushort*)(ws + 12189696);   // 131,072 (OkT contiguous after)
  ushort* Qn_bf  = (ushort*)(ws + 13369344);   // 1,048,576 elems
  ushort* mW_bf  = (ushort*)(ws + 13893632);
  ushort* Wup_bf = (ushort*)(ws + 14417920);
  ushort* Wdn_bf = (ushort*)(ws + 18612224);
  float*  qp       = ws + 20709376;  // 2048
  float*  vraw     = ws + 20713472;  // 4096
  float*  ssq_part = ws + 20717568;  // 512  -- zero region start
  float*  hpart    = ws + 20718080;  // 64   -- zero region end (576 total)
  ushort* W_bf = (ushort*)(ws + 20750976);
  const size_t NEED_BF = (size_t)(20750976 + 67108864) * 4;
  const bool useBf = ws_size >= NEED_BF;

  k_cvt3<<<13312, 256, 0, stream>>>(mW, mW_bf, 1048576L,
                                    WupW, Wup_bf, 8388608L,
                                    WdownW, Wdn_bf, 4194304L);

  hipMemsetAsync(ssq_part, 0, 576*sizeof(float), stream);
  k_sn_v<<<dim3(128,8), 512, 0, stream>>>(hqW, hkW, uq, uk, vpart,
                                          useBf ? W_bf : nullptr);
  k_sn_norm<<<8, 512, 0, stream>>>(vpart, vraw, qpb);
  if (!useBf)
    k_sn_s<<<dim3(128,8), 256, 0, stream>>>(hqW, hkW, vraw, ssq_part);

  k_embed_ln<<<2048, 256, 0, stream>>>(inputs, carry_inputs, halted32,
                                       embedding, pos_emb, in_g, in_b, X);

  for (int cyc = 0; cyc < 2; cyc++){
    for (int k = 0; k < 4; k++){
      if (k == 0){
        if (cyc == 0)
          k_ln1<1,1,1,0><<<dim3(32,4), 512, 0, stream>>>(
              Qa, Qa, X, halted32, init_hidden, carry_hidden,
              Qn_bf, QnT_bf, qp_part, g1 + k*DMD, b1 + k*DMD, nullptr, nullptr);
        else
          k_ln1<2,1,1,0><<<dim3(32,4), 512, 0, stream>>>(
              Qa, Qa, X, nullptr, nullptr, nullptr,
              Qn_bf, QnT_bf, qp_part, g1 + k*DMD, b1 + k*DMD, nullptr, nullptr);
      } else {
        k_ln1<0,1,1,0><<<dim3(32,4), 512, 0, stream>>>(
            Qa, nullptr, nullptr, nullptr, nullptr, nullptr,
            Qn_bf, QnT_bf, qp_part, g1 + k*DMD, b1 + k*DMD, nullptr, nullptr);
      }
      k_qp2<<<4, 512, 0, stream>>>(qp_part, qp, qpb);
      // O(q|k) = qp @ W^T; W_bf linear, permutation applied on read (PERM=1)
      if (useBf)
        mm_bt<64,64,32,32,6,1,0,1,0,0,1><<<dim3(512,1,2), 256, 0, stream>>>(
            qpb + (long)k*2*32768, W_bf + (long)k*2*16777216, OqT,
            32768, 512, 32768, 16777216, 131072,
            nullptr, nullptr, nullptr, nullptr, nullptr, 0,
            (cyc == 0) ? (ssq_part + k*128) : nullptr, nullptr);
      else
        k_proj<<<dim3(8192,2), 256, 0, stream>>>(hqW, hkW, qp, OqT, OqT + 131072, k);
      // Pq|Pk = elu((Qn @ O)/sigma + bias)+1
      mm_bt<64,64,32,32,1,1,1,0><<<dim3(1,8,8), 256, 0, stream>>>(
          Qn_bf, OqT, Pq_bf, 64, 512, 262144, 32768, 32768,
          BQb + k*64, BKb + k*64, nullptr, nullptr, nullptr, 0,
          nullptr, ssq_part + k*128);
      // fused attention: Wm + rowsum + Att + (/Nrm - Qn) -> m_bf
      k_attn<<<dim3(8,8,4), 256, 0, stream>>>(Pq_bf, QnT_bf, Qn_bf, m_bf);
      // Qi = Qa + softplus(dt)*(m @ mW^T + mb) -> Qb (f32), 64x64 tile
      mm_bt<64,64,32,32,3,0,0,0><<<dim3(8,32,1), 256, 0, stream>>>(
          m_bf, mW_bf + (long)k*262144, Qb, 512, 512, 0, 0, 0,
          mb + k*DMD, nullptr, Qa, nullptr, dt, k, nullptr, nullptr);
      // LN2 -> Qn_bf only
      k_ln1<0,0,0,0><<<dim3(32,4), 512, 0, stream>>>(
          Qb, nullptr, nullptr, nullptr, nullptr, nullptr,
          Qn_bf, nullptr, nullptr, g2 + k*DMD, b2 + k*DMD, nullptr, nullptr);
      // GU = Qn2 @ WupW^T (bf16 out), TRN grid for B-panel L2 reuse
      mm_bt<128,128,64,64,0,1,0,0,0,1><<<dim3(16,32,1), 256, 0, stream>>>(
          Qn_bf, Wup_bf + (long)k*2097152, GU_bf, 4096, 512, 0, 0, 0,
          nullptr, nullptr, nullptr, nullptr, nullptr, 0, nullptr, nullptr);
      k_convfuse<<<2048, 256, 0, stream>>>(GU_bf, convW + (long)k*2048*3, Hc_bf);
      // Q_next = Qi + Hc @ WdownW^T -> Qa (f32), 64x64 tile; last iter also -> out
      float* aux = (cyc == 1 && k == 3) ? (out + OFF_Q) : nullptr;
      mm_bt<64,64,32,32,4,0,0,0><<<dim3(8,32,1), 256, 0, stream>>>(
          Hc_bf, Wdn_bf + (long)k*1048576, Qa, 512, 2048, 0, 0, 0,
          nullptr, nullptr, Qb, nullptr, nullptr, 0, aux, nullptr);
    }
  }

  // final LN (+halt dot) + lm head (CVTB NT-loads from f32, TRN grid,
  // NTC non-temporal logits stores: keep lm_head resident in LLC)
  k_ln1<0,0,0,1><<<dim3(32,4), 512, 0, stream>>>(
      Qa, nullptr, nullptr, nullptr, nullptr, nullptr,
      Qn_bf, nullptr, nullptr, fin_g, fin_b, halt_W, hpart);
  mm_bt<128,128,64,64,0,0,0,0,1,1,0,1><<<dim3(16,250,1), 256, 0, stream>>>(
      Qn_bf, (const ushort*)lm_head, out, 32000, 512, 0, 0, 0,
      nullptr, nullptr, nullptr, nullptr, nullptr, 0, nullptr, nullptr);
  k_fin<<<1, 64, 0, stream>>>(halted32, steps, hpart, halt_b,
                              out + OFF_HALT, out + OFF_STEPS, out + OFF_HALTED);
}

// Round 16
// 1519.877 us; speedup vs baseline: 1.0253x; 1.0253x over previous
//
#include <hip/hip_runtime.h>
#include <stdint.h>

#define DMD 512
#define NSEQ 512
#define NBATCH 4
#define WROWS 32768
#define VOCAB 32000

#define OFF_HALT   65536000L
#define OFF_Q      65536004L
#define OFF_STEPS  66584580L
#define OFF_HALTED 66584584L

typedef __attribute__((ext_vector_type(8))) short short8v;
typedef __attribute__((ext_vector_type(4))) float f32x4;

__device__ __forceinline__ ushort f2bf(float f){
  uint u = __builtin_bit_cast(uint, f);
  u += 0x7fffu + ((u >> 16) & 1u);
  return (ushort)(u >> 16);
}
__device__ __forceinline__ float bf2f(ushort h){
  return __builtin_bit_cast(float, (uint)h << 16);
}

// ---------------- reductions ----------------
__device__ __forceinline__ float block_reduce_sum256(float v, float* red){
  int t = threadIdx.x;
  red[t] = v; __syncthreads();
  for (int o = 128; o; o >>= 1){
    if (t < o) red[t] += red[t+o];
    __syncthreads();
  }
  float r = red[0]; __syncthreads();
  return r;
}

// ============ mega-fused LayerNorm ============
template<int MODE, int TR, int QP, int HALT>
__global__ __launch_bounds__(512) void k_ln1(
    const float* in, float* QaW, const float* X,
    const int* halted32, const float* ih, const float* ch,
    ushort* __restrict__ outb, ushort* __restrict__ outT,
    float* __restrict__ qp_part,
    const float* __restrict__ g, const float* __restrict__ b,
    const float* __restrict__ hW, float* __restrict__ hpart)
{
  __shared__ ushort lt[TR ? 16 : 1][TR ? 520 : 1];
  __shared__ float red[QP ? 4096 : 1];
  const int bb = blockIdx.y, rg = blockIdx.x;
  const int n0 = rg*16;
  const int tid = threadIdx.x, wave = tid >> 6, lane = tid & 63;
  const int c8 = lane*8;
  float qacc[8] = {};
  #pragma unroll
  for (int rr = 0; rr < 2; rr++){
    const int n = n0 + wave*2 + rr;
    const long rowo = (long)bb*262144 + (long)n*512;
    float x[8];
    if (MODE == 1){
      bool hall = (halted32[0] != 0);
      #pragma unroll
      for (int i = 0; i < 8; i++){
        float base = hall ? ih[c8+i] : ch[rowo + c8 + i];
        x[i] = base + X[rowo + c8 + i];
      }
      #pragma unroll
      for (int i = 0; i < 8; i++) QaW[rowo + c8 + i] = x[i];
    } else if (MODE == 2){
      #pragma unroll
      for (int i = 0; i < 8; i++) x[i] = in[rowo + c8 + i] + X[rowo + c8 + i];
      #pragma unroll
      for (int i = 0; i < 8; i++) QaW[rowo + c8 + i] = x[i];
    } else {
      float4 a0 = *(const float4*)(in + rowo + c8);
      float4 a1 = *(const float4*)(in + rowo + c8 + 4);
      x[0]=a0.x; x[1]=a0.y; x[2]=a0.z; x[3]=a0.w;
      x[4]=a1.x; x[5]=a1.y; x[6]=a1.z; x[7]=a1.w;
    }
    float s = 0.f, sq = 0.f;
    #pragma unroll
    for (int i = 0; i < 8; i++){ s += x[i]; sq += x[i]*x[i]; }
    #pragma unroll
    for (int m = 32; m; m >>= 1){
      s  += __shfl_xor(s, m);
      sq += __shfl_xor(sq, m);
    }
    float mu = s*(1.f/512.f);
    float var = sq*(1.f/512.f) - mu*mu;
    float rs = rsqrtf(var + 1e-5f);
    float hd = 0.f;
    short8v ov;
    #pragma unroll
    for (int i = 0; i < 8; i++){
      float o = (x[i]-mu)*rs*g[c8+i] + b[c8+i];
      ov[i] = (short)f2bf(o);
      if (QP) qacc[i] += o;
      if (HALT) hd += o * hW[c8+i];
    }
    *(short8v*)&outb[rowo + c8] = ov;
    if (TR) *(short8v*)&lt[n & 15][c8] = ov;
    if (HALT){
      #pragma unroll
      for (int m = 32; m; m >>= 1) hd += __shfl_xor(hd, m);
      if (lane == 0) atomicAdd(&hpart[bb], hd);
    }
  }
  if (QP){
    #pragma unroll
    for (int i = 0; i < 8; i++) red[wave*512 + c8 + i] = qacc[i];
    __syncthreads();
    if (wave == 0){
      #pragma unroll
      for (int i = 0; i < 8; i++){
        int c = c8 + i;
        float s = 0.f;
        #pragma unroll
        for (int w = 0; w < 8; w++) s += red[w*512 + c];
        qp_part[((long)bb*32 + rg)*512 + c] = s;
      }
    }
  }
  if (TR){
    __syncthreads();
    #pragma unroll 4
    for (int p = 0; p < 16; p++){
      int d = p*32 + (tid >> 4);
      int n = tid & 15;
      outT[(long)bb*262144 + (long)d*512 + n0 + n] = lt[n][d];
    }
  }
}

// embed + pos + LN fused -> X
__global__ void k_embed_ln(const int* __restrict__ inputs, const int* __restrict__ cinputs,
                           const int* __restrict__ halted32,
                           const float* __restrict__ emb, const float* __restrict__ pos,
                           const float* __restrict__ g, const float* __restrict__ b,
                           float* __restrict__ X){
  __shared__ float red[256];
  int r = blockIdx.x; int t = threadIdx.x;
  int n = r & 511;
  bool hall = (halted32[0] != 0);
  int tok = hall ? inputs[r] : cinputs[r];
  const float* e = emb + (long)tok*DMD;
  const float* p = pos + (long)n*DMD;
  float v0 = e[t]+p[t], v1 = e[t+256]+p[t+256];
  float mu = block_reduce_sum256(v0+v1, red) * (1.f/DMD);
  float d0 = v0-mu, d1 = v1-mu;
  float var = block_reduce_sum256(d0*d0+d1*d1, red) * (1.f/DMD);
  float rs = rsqrtf(var + 1e-5f);
  X[(long)r*DMD+t]     = d0*rs*g[t]     + b[t];
  X[(long)r*DMD+t+256] = d1*rs*g[t+256] + b[t+256];
}

// ---------------- spectral norm v-pass + LINEAR bf16 W copy ---------------
__global__ __launch_bounds__(512) void k_sn_v(
    const float* __restrict__ hqW, const float* __restrict__ hkW,
    const float* __restrict__ uq, const float* __restrict__ uk,
    float* __restrict__ vpart, ushort* __restrict__ Wbf){
  __shared__ float red[8*520];
  int z = blockIdx.y; int k = z >> 1, qk = z & 1;
  const float* W = (qk ? hkW : hqW) + (long)k*WROWS*DMD;
  const float* u = (qk ? uk : uq) + (long)k*WROWS;
  ushort* Wb = Wbf ? (Wbf + (long)z*WROWS*DMD) : nullptr;
  int t = threadIdx.x;
  int c8 = (t & 63) * 8;
  int rsub = t >> 6;
  int r0 = blockIdx.x * 256;
  float acc[8] = {};
  for (int r = rsub; r < 256; r += 16){
    int ra = r0 + r, rb = r0 + r + 8;
    long offa = (long)ra*DMD + c8, offb = (long)rb*DMD + c8;
    f32x4 a0 = __builtin_nontemporal_load((const f32x4*)(W + offa));
    f32x4 a1 = __builtin_nontemporal_load((const f32x4*)(W + offa + 4));
    f32x4 b0 = __builtin_nontemporal_load((const f32x4*)(W + offb));
    f32x4 b1 = __builtin_nontemporal_load((const f32x4*)(W + offb + 4));
    float ua = u[ra], ub = u[rb];
    float av[8] = {a0[0],a0[1],a0[2],a0[3],a1[0],a1[1],a1[2],a1[3]};
    float bv[8] = {b0[0],b0[1],b0[2],b0[3],b1[0],b1[1],b1[2],b1[3]};
    #pragma unroll
    for (int i = 0; i < 8; i++) acc[i] += av[i]*ua + bv[i]*ub;
    if (Wb){
      short8v oa, ob;
      #pragma unroll
      for (int i = 0; i < 8; i++){ oa[i] = (short)f2bf(av[i]); ob[i] = (short)f2bf(bv[i]); }
      __builtin_nontemporal_store(oa, (short8v*)(Wb + offa));
      __builtin_nontemporal_store(ob, (short8v*)(Wb + offb));
    }
  }
  #pragma unroll
  for (int i = 0; i < 8; i++) red[rsub*520 + c8 + i] = acc[i];
  __syncthreads();
  if (rsub == 0){
    #pragma unroll
    for (int i = 0; i < 8; i++){
      int c = c8 + i;
      float s = 0.f;
      #pragma unroll
      for (int w = 0; w < 8; w++) s += red[w*520 + c];
      vpart[((long)z*128 + blockIdx.x)*512 + c] = s;
    }
  }
}

// reduce vpart -> normalized v; write qpb row4 = v-hat, zero rows 5..63
__global__ __launch_bounds__(512) void k_sn_norm(const float* __restrict__ vpart,
                                                 float* __restrict__ vraw,
                                                 ushort* __restrict__ qpb){
  __shared__ float red[512];
  int z = blockIdx.x; int t = threadIdx.x;
  float s = 0.f;
  for (int c = 0; c < 128; c++) s += vpart[((long)z*128 + c)*512 + t];
  red[t] = s*s; __syncthreads();
  for (int o = 256; o; o >>= 1){
    if (t < o) red[t] += red[t+o];
    __syncthreads();
  }
  float nrm = sqrtf(red[0]);
  float v = s / (nrm + 1e-12f);
  vraw[z*512 + t] = v;
  ushort* p = qpb + (long)z*32768;
  p[4*512 + t] = f2bf(v);
  for (int r = 5; r < 64; r++) p[r*512 + t] = 0;
}

// f32 fallback sigma pass
__global__ void k_sn_s(const float* __restrict__ hqW, const float* __restrict__ hkW,
                       const float* __restrict__ vraw, float* __restrict__ ssqp){
  int z = blockIdx.y; int k = z >> 1, qk = z & 1;
  const float* W = (qk ? hkW : hqW) + (long)k*WROWS*DMD;
  const float* v = vraw + z*DMD;
  int wave = threadIdx.x >> 6, lane = threadIdx.x & 63;
  float vreg[8];
  #pragma unroll
  for (int i = 0; i < 8; i++) vreg[i] = v[lane + 64*i];
  int r0 = blockIdx.x*256 + wave*64;
  float acc = 0.f;
  for (int r = r0; r < r0+64; r++){
    float p = 0.f;
    #pragma unroll
    for (int i = 0; i < 8; i++)
      p += W[(long)r*DMD + lane + 64*i] * vreg[i];
    for (int off = 32; off; off >>= 1) p += __shfl_down(p, off);
    if (lane == 0) acc += p*p;
  }
  if (lane == 0) atomicAdd(&ssqp[z*64 + (blockIdx.x & 63)], acc);
}

// f32 fallback proj
__global__ void k_proj(const float* __restrict__ hqW, const float* __restrict__ hkW,
                       const float* __restrict__ qp,
                       ushort* __restrict__ OqT, ushort* __restrict__ OkT, int k){
  int z = blockIdx.y;
  const float* W = (z ? hkW : hqW) + (long)k*WROWS*DMD;
  ushort* O = z ? OkT : OqT;
  int wave = threadIdx.x >> 6, lane = threadIdx.x & 63;
  long r = (long)blockIdx.x*4 + wave;
  float a0=0,a1=0,a2=0,a3=0;
  for (int j = lane; j < DMD; j += 64){
    float w = W[r*DMD + j];
    a0 += w*qp[j]; a1 += w*qp[DMD+j]; a2 += w*qp[2*DMD+j]; a3 += w*qp[3*DMD+j];
  }
  for (int off = 32; off; off >>= 1){
    a0 += __shfl_down(a0,off); a1 += __shfl_down(a1,off);
    a2 += __shfl_down(a2,off); a3 += __shfl_down(a3,off);
  }
  if (lane == 0){
    int d = (int)(r >> 6), e = (int)(r & 63);
    long o = (long)e*512 + d;
    O[o] = f2bf(a0); O[32768+o] = f2bf(a1);
    O[2*32768+o] = f2bf(a2); O[3*32768+o] = f2bf(a3);
  }
}

// ---------------- bf16 MFMA GEMM: C = A . B^T (+epilogue), BK=64 ----------
// EPI: 0 none | 1 elu(acc*invsigma+bias[col])+1 | 3 res+sp*(acc+bias[col])
//      | 4 acc+res (+aux store) | 6 proj (rows<4 bf16; row4 -> ssq atomic)
// CVTB: B operand is f32 global, converted during staging (regular loads:
//       L2 panel reuse across row-blocks is the point of TRN).
// TRN: tm from blockIdx.x, tn from blockIdx.y (B-panel L2 reuse).
// PERM: B tile row p gathers original row (p&511)*64 + (p>>9).
// NTC: non-temporal C stores (touch-once output; keep B resident in LLC).
template<int BM, int BN, int WM, int WN, int EPI, int BFOUT, int DUAL, int RSUM,
         int CVTB = 0, int TRN = 0, int PERM = 0, int NTC = 0>
__global__ __launch_bounds__(256) void mm_bt(
    const ushort* __restrict__ A, const ushort* __restrict__ B, void* __restrict__ C,
    int N, int K, long sA, long sB, long sC,
    const float* __restrict__ bias, const float* __restrict__ bias2,
    const float* __restrict__ res, const ushort* __restrict__ resb,
    const float* __restrict__ dtp, int dtidx,
    float* __restrict__ aux, const float* __restrict__ ssqp)
{
  __shared__ ushort As[BM*64];
  __shared__ ushort Bs[BN*64];
  const int z = blockIdx.z;
  const float* biasz = bias;
  if (DUAL){
    A += (long)(z & 3)*sA;
    if (z >= 4) biasz = bias2;
  } else {
    A += (long)z*sA;
  }
  if (!CVTB) B += (long)z*sB;
  const int tm = (TRN ? blockIdx.x : blockIdx.y)*BM;
  const int tn = DUAL ? 0 : (TRN ? blockIdx.y : blockIdx.x)*BN;
  const int tid = threadIdx.x;
  const int wid = tid >> 6, lane = tid & 63;
  constexpr int NWN = BN/WN;
  const int wr = wid / NWN, wc = wid % NWN;
  constexpr int FM = WM/16, FN = WN/16;
  const int ln15 = lane & 15, kq = lane >> 4;
  constexpr int LA = BM/32;
  constexpr int LB = BN/32;
  f32x4 acc[FM][FN] = {};

  for (int k0 = 0; k0 < K; k0 += 64){
    #pragma unroll
    for (int l = 0; l < LA; l++){
      int slot = tid + l*256;
      int row = slot >> 3, ch = slot & 7;
      int gch = ch ^ (row & 7);
      const char* g = (const char*)(A + (long)(tm+row)*K + k0) + gch*16;
      ushort* lp = As + (size_t)(wid*64 + l*256)*8;
      __builtin_amdgcn_global_load_lds((const __attribute__((address_space(1))) void*)g,
                                       (__attribute__((address_space(3))) void*)lp, 16, 0, 0);
    }
    #pragma unroll
    for (int l = 0; l < LB; l++){
      int slot = tid + l*256;
      int row = slot >> 3, ch = slot & 7;
      int gch = ch ^ (row & 7);
      if (CVTB){
        const float* Bf = (const float*)B;
        const float* src = Bf + (long)(tn+row)*K + k0 + gch*8;
        float4 v0 = *(const float4*)src;
        float4 v1 = *(const float4*)(src + 4);
        float vv[8] = {v0.x,v0.y,v0.z,v0.w,v1.x,v1.y,v1.z,v1.w};
        short8v o;
        #pragma unroll
        for (int i = 0; i < 8; i++) o[i] = (short)f2bf(vv[i]);
        *(short8v*)&Bs[(size_t)slot*8] = o;
      } else {
        long brow;
        if (PERM){
          int p = tn + row;
          brow = (long)((p & 511)*64 + (p >> 9));
        } else {
          brow = (long)(tn + row);
        }
        const char* g = (const char*)(B + brow*K + k0) + gch*16;
        ushort* lp = Bs + (size_t)(wid*64 + l*256)*8;
        __builtin_amdgcn_global_load_lds((const __attribute__((address_space(1))) void*)g,
                                         (__attribute__((address_space(3))) void*)lp, 16, 0, 0);
      }
    }
    __syncthreads();
    #pragma unroll
    for (int ks = 0; ks < 2; ks++){
      short8v af[FM], bfr[FN];
      #pragma unroll
      for (int i = 0; i < FM; i++){
        int row = wr*WM + i*16 + ln15;
        af[i] = *(const short8v*)&As[row*64 + (((ks*4+kq) ^ (row&7))*8)];
      }
      #pragma unroll
      for (int j = 0; j < FN; j++){
        int row = wc*WN + j*16 + ln15;
        bfr[j] = *(const short8v*)&Bs[row*64 + (((ks*4+kq) ^ (row&7))*8)];
      }
      #pragma unroll
      for (int i = 0; i < FM; i++)
        #pragma unroll
        for (int j = 0; j < FN; j++)
          acc[i][j] = __builtin_amdgcn_mfma_f32_16x16x32_bf16(af[i], bfr[j], acc[i][j], 0, 0, 0);
    }
    __syncthreads();
  }

  float sp = 0.f, invs = 1.f;
  if (EPI == 3) sp = log1pf(expf(dtp[dtidx]));
  if (EPI == 1){
    const float* sq = ssqp + (DUAL ? (z >> 2)*64 : 0);
    float s2 = 0.f;
    for (int i = 0; i < 64; i++) s2 += sq[i];
    invs = (sqrtf(s2) + 1e-12f) / s2;
  }
  float* Cf = (float*)C + (long)z*sC;
  ushort* Cb = (ushort*)C + (long)z*sC;
  const float* rz = res ? (res + (long)z*sC) : nullptr;
  float sacc = 0.f;
  #pragma unroll
  for (int i = 0; i < FM; i++){
    int row0 = tm + wr*WM + i*16 + kq*4;
    #pragma unroll
    for (int j = 0; j < FN; j++){
      int col = tn + wc*WN + j*16 + ln15;
      #pragma unroll
      for (int r = 0; r < 4; r++){
        int row = row0 + r;
        long idx = (long)row*N + col;
        float v = acc[i][j][r];
        if (EPI == 6){
          if (row < 4) Cb[idx] = f2bf(v);
          else if (row == 4) sacc += v*v;
          continue;
        }
        if (EPI == 1){ v = v*invs + biasz[col]; v = v > 0.f ? v : expm1f(v); v += 1.f; }
        else if (EPI == 3){ v = rz[idx] + sp*(v + biasz[col]); }
        else if (EPI == 4){ v = v + rz[idx]; if (aux) aux[idx] = v; }
        if (BFOUT) Cb[idx] = f2bf(v);
        else if (NTC) __builtin_nontemporal_store(v, &Cf[idx]);
        else       Cf[idx] = v;
      }
    }
  }
  if (EPI == 6 && aux){
    sacc += __shfl_xor(sacc, 1); sacc += __shfl_xor(sacc, 2);
    sacc += __shfl_xor(sacc, 4); sacc += __shfl_xor(sacc, 8);
    if (wr == 0 && kq == 1 && ln15 == 0)
      atomicAdd(&aux[(long)z*64 + ((int)blockIdx.x & 63)], sacc);
  }
}

// ---------------- fused attention: S=Pq.Pk^T -> relu^2 -> rowsum + @Qn ----
__global__ __launch_bounds__(256) void k_attn(
    const ushort* __restrict__ Pqk, const ushort* __restrict__ QnT,
    const ushort* __restrict__ Qn, ushort* __restrict__ m_out)
{
  __shared__ ushort Aq[64*64];
  __shared__ ushort Bk[64*64];
  __shared__ ushort Qs[64*64];
  __shared__ ushort Ws[64*72];
  __shared__ float nrmL[2][64];
  const int cg = blockIdx.x, nt = blockIdx.y, b = blockIdx.z;
  const int tid = threadIdx.x, wid = tid >> 6;
  const int lane = tid & 63, ln15 = lane & 15, kq = lane >> 4;
  const int wr = wid >> 1, wc = wid & 1;
  const ushort* Pq  = Pqk + (long)b*32768 + (long)nt*4096;
  const ushort* Pk0 = Pqk + 131072 + (long)b*32768;
  const ushort* Qt  = QnT + (long)b*262144 + (long)(cg*64)*512;

  #pragma unroll
  for (int l = 0; l < 2; l++){
    int slot = tid + l*256;
    int row = slot >> 3, gch = (slot & 7) ^ (row & 7);
    __builtin_amdgcn_global_load_lds(
        (const __attribute__((address_space(1))) void*)((const char*)(Pq + (long)row*64) + gch*16),
        (__attribute__((address_space(3))) void*)(Aq + (size_t)(wid*64 + l*256)*8), 16, 0, 0);
  }
  f32x4 acc[2][2] = {};
  float nacc[2][4] = {};
  for (int mt = 0; mt < 8; mt++){
    #pragma unroll
    for (int l = 0; l < 2; l++){
      int slot = tid + l*256;
      int row = slot >> 3, gch = (slot & 7) ^ (row & 7);
      __builtin_amdgcn_global_load_lds(
          (const __attribute__((address_space(1))) void*)((const char*)(Pk0 + (long)mt*4096 + (long)row*64) + gch*16),
          (__attribute__((address_space(3))) void*)(Bk + (size_t)(wid*64 + l*256)*8), 16, 0, 0);
      __builtin_amdgcn_global_load_lds(
          (const __attribute__((address_space(1))) void*)((const char*)(Qt + (long)row*512 + mt*64) + gch*16),
          (__attribute__((address_space(3))) void*)(Qs + (size_t)(wid*64 + l*256)*8), 16, 0, 0);
    }
    __syncthreads();
    f32x4 sA[2][2] = {};
    #pragma unroll
    for (int ks = 0; ks < 2; ks++){
      short8v af[2], bfr[2];
      #pragma unroll
      for (int i = 0; i < 2; i++){
        int row = wr*32 + i*16 + ln15;
        af[i] = *(const short8v*)&Aq[row*64 + (((ks*4+kq) ^ (row&7))*8)];
      }
      #pragma unroll
      for (int j = 0; j < 2; j++){
        int row = wc*32 + j*16 + ln15;
        bfr[j] = *(const short8v*)&Bk[row*64 + (((ks*4+kq) ^ (row&7))*8)];
      }
      #pragma unroll
      for (int i = 0; i < 2; i++)
        #pragma unroll
        for (int j = 0; j < 2; j++)
          sA[i][j] = __builtin_amdgcn_mfma_f32_16x16x32_bf16(af[i], bfr[j], sA[i][j], 0, 0, 0);
    }
    float t[2][4] = {};
    #pragma unroll
    for (int i = 0; i < 2; i++)
      #pragma unroll
      for (int j = 0; j < 2; j++)
        #pragma unroll
        for (int r = 0; r < 4; r++){
          float v = fmaxf(sA[i][j][r], 0.f); v = v*v;
          t[i][r] += v;
          int row = wr*32 + i*16 + kq*4 + r;
          int col = wc*32 + j*16 + ln15;
          Ws[row*72 + col] = f2bf(v);
        }
    #pragma unroll
    for (int i = 0; i < 2; i++)
      #pragma unroll
      for (int r = 0; r < 4; r++){
        float x = t[i][r];
        x += __shfl_xor(x, 1); x += __shfl_xor(x, 2);
        x += __shfl_xor(x, 4); x += __shfl_xor(x, 8);
        nacc[i][r] += x;
      }
    __syncthreads();
    #pragma unroll
    for (int ks = 0; ks < 2; ks++){
      short8v af[2], bfr[2];
      #pragma unroll
      for (int i = 0; i < 2; i++){
        int row = wr*32 + i*16 + ln15;
        af[i] = *(const short8v*)&Ws[row*72 + (ks*4+kq)*8];
      }
      #pragma unroll
      for (int j = 0; j < 2; j++){
        int row = wc*32 + j*16 + ln15;
        bfr[j] = *(const short8v*)&Qs[row*64 + (((ks*4+kq) ^ (row&7))*8)];
      }
      #pragma unroll
      for (int i = 0; i < 2; i++)
        #pragma unroll
        for (int j = 0; j < 2; j++)
          acc[i][j] = __builtin_amdgcn_mfma_f32_16x16x32_bf16(af[i], bfr[j], acc[i][j], 0, 0, 0);
    }
    __syncthreads();
  }
  if (ln15 == 0){
    #pragma unroll
    for (int i = 0; i < 2; i++)
      #pragma unroll
      for (int r = 0; r < 4; r++)
        nrmL[wc][wr*32 + i*16 + kq*4 + r] = nacc[i][r];
  }
  __syncthreads();
  #pragma unroll
  for (int i = 0; i < 2; i++){
    #pragma unroll
    for (int r = 0; r < 4; r++){
      int rowl = wr*32 + i*16 + kq*4 + r;
      float Nr = fabsf(nrmL[0][rowl] + nrmL[1][rowl]) + 1.f;
      int n = nt*64 + rowl;
      #pragma unroll
      for (int j = 0; j < 2; j++){
        int col = cg*64 + wc*32 + j*16 + ln15;
        long idx = (long)b*262144 + (long)n*512 + col;
        m_out[idx] = f2bf(acc[i][j][r]/Nr - bf2f(Qn[idx]));
      }
    }
  }
}

// ---------------- small kernels ----------------
__global__ void k_qp2(const float* __restrict__ part, float* __restrict__ qp,
                      ushort* __restrict__ qpb){
  int b = blockIdx.x, t = threadIdx.x;
  float s = 0.f;
  #pragma unroll
  for (int c = 0; c < 32; c++) s += part[((long)b*32 + c)*512 + t];
  float val = s * (1.f/512.f);
  qp[b*512 + t] = val;
  ushort bv = f2bf(val);
  #pragma unroll
  for (int z = 0; z < 8; z++)
    qpb[(long)z*32768 + (long)b*512 + t] = bv;
}

__global__ void k_convfuse(const ushort* __restrict__ GU, const float* __restrict__ w,
                           ushort* __restrict__ Hc){
  int r = blockIdx.x;
  int n = r & 511;
  int c = threadIdx.x * 8;
  long base = (long)r*4096 + c;
  float o[8] = {};
  if (n > 0){
    short8v gv = *(const short8v*)&GU[base-4096];
    short8v uv = *(const short8v*)&GU[base-4096+2048];
    #pragma unroll
    for (int i = 0; i < 8; i++){
      float g = bf2f((ushort)gv[i]), u = bf2f((ushort)uv[i]);
      o[i] += g/(1.f+expf(-g))*u * w[(c+i)*3+0];
    }
  }
  {
    short8v gv = *(const short8v*)&GU[base];
    short8v uv = *(const short8v*)&GU[base+2048];
    #pragma unroll
    for (int i = 0; i < 8; i++){
      float g = bf2f((ushort)gv[i]), u = bf2f((ushort)uv[i]);
      o[i] += g/(1.f+expf(-g))*u * w[(c+i)*3+1];
    }
  }
  if (n < 511){
    short8v gv = *(const short8v*)&GU[base+4096];
    short8v uv = *(const short8v*)&GU[base+4096+2048];
    #pragma unroll
    for (int i = 0; i < 8; i++){
      float g = bf2f((ushort)gv[i]), u = bf2f((ushort)uv[i]);
      o[i] += g/(1.f+expf(-g))*u * w[(c+i)*3+2];
    }
  }
  short8v ov;
  #pragma unroll
  for (int i = 0; i < 8; i++) ov[i] = (short)f2bf(o[i]);
  *(short8v*)&Hc[(long)r*2048 + c] = ov;
}

__global__ void k_cvt3(const float* __restrict__ s0, ushort* __restrict__ d0, long n0,
                       const float* __restrict__ s1, ushort* __restrict__ d1, long n1,
                       const float* __restrict__ s2, ushort* __restrict__ d2, long n2){
  long i = ((long)blockIdx.x*256 + threadIdx.x)*4;
  const float* s; ushort* d; long off;
  if (i < n0){ s = s0; d = d0; off = i; }
  else if (i < n0 + n1){ s = s1; d = d1; off = i - n0; }
  else { s = s2; d = d2; off = i - n0 - n1; }
  float4 v = *(const float4*)(s + off);
  ushort4 o;
  o.x = f2bf(v.x); o.y = f2bf(v.y); o.z = f2bf(v.z); o.w = f2bf(v.w);
  *(ushort4*)(d + off) = o;
}

__global__ void k_fin(const int* __restrict__ halted32, const int* __restrict__ steps,
                      const float* __restrict__ hpart, const float* __restrict__ hb,
                      float* __restrict__ o_halt, float* __restrict__ o_steps,
                      float* __restrict__ o_halted){
  int t = threadIdx.x;
  if (t < NBATCH){
    o_halt[t] = hpart[t]*(1.f/512.f) + hb[0];
    bool hall = (halted32[0] != 0);
    int ns = (hall ? 0 : steps[t]) + 1;
    o_steps[t] = (float)ns;
    o_halted[t] = ns >= 6 ? 1.f : 0.f;
  }
}

// ---------------- launch ----------------
extern "C" void kernel_launch(void* const* d_in, const int* in_sizes, int n_in,
                              void* d_out, int out_size, void* d_ws, size_t ws_size,
                              hipStream_t stream)
{
  const int*     inputs       = (const int*)d_in[0];
  const int*     halted32     = (const int*)d_in[2];
  const int*     steps        = (const int*)d_in[3];
  const float*   carry_hidden = (const float*)d_in[4];
  const int*     carry_inputs = (const int*)d_in[5];
  const float*   embedding    = (const float*)d_in[7];
  const float*   pos_emb      = (const float*)d_in[8];
  const float*   in_g = (const float*)d_in[9];
  const float*   in_b = (const float*)d_in[10];
  const float*   init_hidden = (const float*)d_in[11];
  const float*   dt   = (const float*)d_in[12];
  const float*   mW   = (const float*)d_in[13];
  const float*   mb   = (const float*)d_in[14];
  const float*   hqW  = (const float*)d_in[15];
  const float*   hkW  = (const float*)d_in[16];
  const float*   uq   = (const float*)d_in[17];
  const float*   uk   = (const float*)d_in[18];
  const float*   BQb  = (const float*)d_in[19];
  const float*   BKb  = (const float*)d_in[20];
  const float*   g1   = (const float*)d_in[21];
  const float*   b1   = (const float*)d_in[22];
  const float*   g2   = (const float*)d_in[23];
  const float*   b2   = (const float*)d_in[24];
  const float*   WupW = (const float*)d_in[25];
  const float*   convW= (const float*)d_in[26];
  const float*   WdownW=(const float*)d_in[27];
  const float*   fin_g= (const float*)d_in[28];
  const float*   fin_b= (const float*)d_in[29];
  const float*   halt_W=(const float*)d_in[30];
  const float*   halt_b=(const float*)d_in[31];
  const float*   lm_head=(const float*)d_in[32];
  float* out = (float*)d_out;

  float* ws = (float*)d_ws;
  float*  X    = ws;
  float*  Qa   = ws +  1048576;
  float*  Qb   = ws +  2097152;
  ushort* qpb  = (ushort*)(ws + 3145728);      // 8 x 64 x 512 bf16
  float*  vpart  = ws + 3276800;               // 8 x 128 x 512 f32 (prologue only)
  float*  qp_part= ws + 3801088;               // 4 x 32 x 512 f32
  ushort* GU_bf  = (ushort*)(ws +  4194304);   // 8,388,608 elems
  ushort* Hc_bf  = (ushort*)(ws +  8388608);   // 4,194,304 elems
  ushort* m_bf   = (ushort*)(ws + 10485760);   // 1,048,576 elems
  ushort* QnT_bf = (ushort*)(ws + 11534336);   // 1,048,576 elems
  ushort* Pq_bf  = (ushort*)(ws + 12058624);   // 131,072 (Pk contiguous after)
  ushort* OqT    = (ushort*)(ws + 12189696);   // 131,072 (OkT contiguous after)
  ushort* Qn_bf  = (ushort*)(ws + 13369344);   // 1,048,576 elems
  ushort* mW_bf  = (ushort*)(ws + 13893632);
  ushort* Wup_bf = (ushort*)(ws + 14417920);
  ushort* Wdn_bf = (ushort*)(ws + 18612224);
  float*  qp       = ws + 20709376;  // 2048
  float*  vraw     = ws + 20713472;  // 4096
  float*  ssq_part = ws + 20717568;  // 512  -- zero region start
  float*  hpart    = ws + 20718080;  // 64   -- zero region end (576 total)
  ushort* W_bf = (ushort*)(ws + 20750976);
  const size_t NEED_BF = (size_t)(20750976 + 67108864) * 4;
  const bool useBf = ws_size >= NEED_BF;

  k_cvt3<<<13312, 256, 0, stream>>>(mW, mW_bf, 1048576L,
                                    WupW, Wup_bf, 8388608L,
                                    WdownW, Wdn_bf, 4194304L);

  hipMemsetAsync(ssq_part, 0, 576*sizeof(float), stream);
  k_sn_v<<<dim3(128,8), 512, 0, stream>>>(hqW, hkW, uq, uk, vpart,
                                          useBf ? W_bf : nullptr);
  k_sn_norm<<<8, 512, 0, stream>>>(vpart, vraw, qpb);
  if (!useBf)
    k_sn_s<<<dim3(128,8), 256, 0, stream>>>(hqW, hkW, vraw, ssq_part);

  k_embed_ln<<<2048, 256, 0, stream>>>(inputs, carry_inputs, halted32,
                                       embedding, pos_emb, in_g, in_b, X);

  for (int cyc = 0; cyc < 2; cyc++){
    for (int k = 0; k < 4; k++){
      if (k == 0){
        if (cyc == 0)
          k_ln1<1,1,1,0><<<dim3(32,4), 512, 0, stream>>>(
              Qa, Qa, X, halted32, init_hidden, carry_hidden,
              Qn_bf, QnT_bf, qp_part, g1 + k*DMD, b1 + k*DMD, nullptr, nullptr);
        else
          k_ln1<2,1,1,0><<<dim3(32,4), 512, 0, stream>>>(
              Qa, Qa, X, nullptr, nullptr, nullptr,
              Qn_bf, QnT_bf, qp_part, g1 + k*DMD, b1 + k*DMD, nullptr, nullptr);
      } else {
        k_ln1<0,1,1,0><<<dim3(32,4), 512, 0, stream>>>(
            Qa, nullptr, nullptr, nullptr, nullptr, nullptr,
            Qn_bf, QnT_bf, qp_part, g1 + k*DMD, b1 + k*DMD, nullptr, nullptr);
      }
      k_qp2<<<4, 512, 0, stream>>>(qp_part, qp, qpb);
      // O(q|k) = qp @ W^T; W_bf linear, permutation applied on read (PERM=1)
      if (useBf)
        mm_bt<64,64,32,32,6,1,0,1,0,0,1><<<dim3(512,1,2), 256, 0, stream>>>(
            qpb + (long)k*2*32768, W_bf + (long)k*2*16777216, OqT,
            32768, 512, 32768, 16777216, 131072,
            nullptr, nullptr, nullptr, nullptr, nullptr, 0,
            (cyc == 0) ? (ssq_part + k*128) : nullptr, nullptr);
      else
        k_proj<<<dim3(8192,2), 256, 0, stream>>>(hqW, hkW, qp, OqT, OqT + 131072, k);
      // Pq|Pk = elu((Qn @ O)/sigma + bias)+1
      mm_bt<64,64,32,32,1,1,1,0><<<dim3(1,8,8), 256, 0, stream>>>(
          Qn_bf, OqT, Pq_bf, 64, 512, 262144, 32768, 32768,
          BQb + k*64, BKb + k*64, nullptr, nullptr, nullptr, 0,
          nullptr, ssq_part + k*128);
      // fused attention: Wm + rowsum + Att + (/Nrm - Qn) -> m_bf
      k_attn<<<dim3(8,8,4), 256, 0, stream>>>(Pq_bf, QnT_bf, Qn_bf, m_bf);
      // Qi = Qa + softplus(dt)*(m @ mW^T + mb) -> Qb (f32), 64x64 tile
      mm_bt<64,64,32,32,3,0,0,0><<<dim3(8,32,1), 256, 0, stream>>>(
          m_bf, mW_bf + (long)k*262144, Qb, 512, 512, 0, 0, 0,
          mb + k*DMD, nullptr, Qa, nullptr, dt, k, nullptr, nullptr);
      // LN2 -> Qn_bf only
      k_ln1<0,0,0,0><<<dim3(32,4), 512, 0, stream>>>(
          Qb, nullptr, nullptr, nullptr, nullptr, nullptr,
          Qn_bf, nullptr, nullptr, g2 + k*DMD, b2 + k*DMD, nullptr, nullptr);
      // GU = Qn2 @ WupW^T (bf16 out), TRN grid for B-panel L2 reuse
      mm_bt<128,128,64,64,0,1,0,0,0,1><<<dim3(16,32,1), 256, 0, stream>>>(
          Qn_bf, Wup_bf + (long)k*2097152, GU_bf, 4096, 512, 0, 0, 0,
          nullptr, nullptr, nullptr, nullptr, nullptr, 0, nullptr, nullptr);
      k_convfuse<<<2048, 256, 0, stream>>>(GU_bf, convW + (long)k*2048*3, Hc_bf);
      // Q_next = Qi + Hc @ WdownW^T -> Qa (f32), 64x64 tile; last iter also -> out
      float* aux = (cyc == 1 && k == 3) ? (out + OFF_Q) : nullptr;
      mm_bt<64,64,32,32,4,0,0,0><<<dim3(8,32,1), 256, 0, stream>>>(
          Hc_bf, Wdn_bf + (long)k*1048576, Qa, 512, 2048, 0, 0, 0,
          nullptr, nullptr, Qb, nullptr, nullptr, 0, aux, nullptr);
    }
  }

  // final LN (+halt dot) + lm head: CVTB regular loads (L2 panel reuse),
  // TRN grid, NTC non-temporal logits stores only.
  k_ln1<0,0,0,1><<<dim3(32,4), 512, 0, stream>>>(
      Qa, nullptr, nullptr, nullptr, nullptr, nullptr,
      Qn_bf, nullptr, nullptr, fin_g, fin_b, halt_W, hpart);
  mm_bt<128,128,64,64,0,0,0,0,1,1,0,1><<<dim3(16,250,1), 256, 0, stream>>>(
      Qn_bf, (const ushort*)lm_head, out, 32000, 512, 0, 0, 0,
      nullptr, nullptr, nullptr, nullptr, nullptr, 0, nullptr, nullptr);
  k_fin<<<1, 64, 0, stream>>>(halted32, steps, hpart, halt_b,
                              out + OFF_HALT, out + OFF_STEPS, out + OFF_HALTED);
}

// Round 17
// 1444.972 us; speedup vs baseline: 1.0784x; 1.0518x over previous
//
#include <hip/hip_runtime.h>
#include <stdint.h>

#define DMD 512
#define NSEQ 512
#define NBATCH 4
#define WROWS 32768
#define VOCAB 32000

#define OFF_HALT   65536000L
#define OFF_Q      65536004L
#define OFF_STEPS  66584580L
#define OFF_HALTED 66584584L

typedef __attribute__((ext_vector_type(8))) short short8v;
typedef __attribute__((ext_vector_type(4))) float f32x4;

__device__ __forceinline__ ushort f2bf(float f){
  uint u = __builtin_bit_cast(uint, f);
  u += 0x7fffu + ((u >> 16) & 1u);
  return (ushort)(u >> 16);
}
__device__ __forceinline__ float bf2f(ushort h){
  return __builtin_bit_cast(float, (uint)h << 16);
}

// ---------------- reductions ----------------
__device__ __forceinline__ float block_reduce_sum256(float v, float* red){
  int t = threadIdx.x;
  red[t] = v; __syncthreads();
  for (int o = 128; o; o >>= 1){
    if (t < o) red[t] += red[t+o];
    __syncthreads();
  }
  float r = red[0]; __syncthreads();
  return r;
}

// ============ mega-fused LayerNorm ============
template<int MODE, int TR, int QP, int HALT>
__global__ __launch_bounds__(512) void k_ln1(
    const float* in, float* QaW, const float* X,
    const int* halted32, const float* ih, const float* ch,
    ushort* __restrict__ outb, ushort* __restrict__ outT,
    float* __restrict__ qp_part,
    const float* __restrict__ g, const float* __restrict__ b,
    const float* __restrict__ hW, float* __restrict__ hpart)
{
  __shared__ ushort lt[TR ? 16 : 1][TR ? 520 : 1];
  __shared__ float red[QP ? 4096 : 1];
  const int bb = blockIdx.y, rg = blockIdx.x;
  const int n0 = rg*16;
  const int tid = threadIdx.x, wave = tid >> 6, lane = tid & 63;
  const int c8 = lane*8;
  float qacc[8] = {};
  #pragma unroll
  for (int rr = 0; rr < 2; rr++){
    const int n = n0 + wave*2 + rr;
    const long rowo = (long)bb*262144 + (long)n*512;
    float x[8];
    if (MODE == 1){
      bool hall = (halted32[0] != 0);
      #pragma unroll
      for (int i = 0; i < 8; i++){
        float base = hall ? ih[c8+i] : ch[rowo + c8 + i];
        x[i] = base + X[rowo + c8 + i];
      }
      #pragma unroll
      for (int i = 0; i < 8; i++) QaW[rowo + c8 + i] = x[i];
    } else if (MODE == 2){
      #pragma unroll
      for (int i = 0; i < 8; i++) x[i] = in[rowo + c8 + i] + X[rowo + c8 + i];
      #pragma unroll
      for (int i = 0; i < 8; i++) QaW[rowo + c8 + i] = x[i];
    } else {
      float4 a0 = *(const float4*)(in + rowo + c8);
      float4 a1 = *(const float4*)(in + rowo + c8 + 4);
      x[0]=a0.x; x[1]=a0.y; x[2]=a0.z; x[3]=a0.w;
      x[4]=a1.x; x[5]=a1.y; x[6]=a1.z; x[7]=a1.w;
    }
    float s = 0.f, sq = 0.f;
    #pragma unroll
    for (int i = 0; i < 8; i++){ s += x[i]; sq += x[i]*x[i]; }
    #pragma unroll
    for (int m = 32; m; m >>= 1){
      s  += __shfl_xor(s, m);
      sq += __shfl_xor(sq, m);
    }
    float mu = s*(1.f/512.f);
    float var = sq*(1.f/512.f) - mu*mu;
    float rs = rsqrtf(var + 1e-5f);
    float hd = 0.f;
    short8v ov;
    #pragma unroll
    for (int i = 0; i < 8; i++){
      float o = (x[i]-mu)*rs*g[c8+i] + b[c8+i];
      ov[i] = (short)f2bf(o);
      if (QP) qacc[i] += o;
      if (HALT) hd += o * hW[c8+i];
    }
    *(short8v*)&outb[rowo + c8] = ov;
    if (TR) *(short8v*)&lt[n & 15][c8] = ov;
    if (HALT){
      #pragma unroll
      for (int m = 32; m; m >>= 1) hd += __shfl_xor(hd, m);
      if (lane == 0) atomicAdd(&hpart[bb], hd);
    }
  }
  if (QP){
    #pragma unroll
    for (int i = 0; i < 8; i++) red[wave*512 + c8 + i] = qacc[i];
    __syncthreads();
    if (wave == 0){
      #pragma unroll
      for (int i = 0; i < 8; i++){
        int c = c8 + i;
        float s = 0.f;
        #pragma unroll
        for (int w = 0; w < 8; w++) s += red[w*512 + c];
        qp_part[((long)bb*32 + rg)*512 + c] = s;
      }
    }
  }
  if (TR){
    __syncthreads();
    #pragma unroll 4
    for (int p = 0; p < 16; p++){
      int d = p*32 + (tid >> 4);
      int n = tid & 15;
      outT[(long)bb*262144 + (long)d*512 + n0 + n] = lt[n][d];
    }
  }
}

// embed + pos + LN fused -> X
__global__ void k_embed_ln(const int* __restrict__ inputs, const int* __restrict__ cinputs,
                           const int* __restrict__ halted32,
                           const float* __restrict__ emb, const float* __restrict__ pos,
                           const float* __restrict__ g, const float* __restrict__ b,
                           float* __restrict__ X){
  __shared__ float red[256];
  int r = blockIdx.x; int t = threadIdx.x;
  int n = r & 511;
  bool hall = (halted32[0] != 0);
  int tok = hall ? inputs[r] : cinputs[r];
  const float* e = emb + (long)tok*DMD;
  const float* p = pos + (long)n*DMD;
  float v0 = e[t]+p[t], v1 = e[t+256]+p[t+256];
  float mu = block_reduce_sum256(v0+v1, red) * (1.f/DMD);
  float d0 = v0-mu, d1 = v1-mu;
  float var = block_reduce_sum256(d0*d0+d1*d1, red) * (1.f/DMD);
  float rs = rsqrtf(var + 1e-5f);
  X[(long)r*DMD+t]     = d0*rs*g[t]     + b[t];
  X[(long)r*DMD+t+256] = d1*rs*g[t+256] + b[t+256];
}

// ---------------- spectral norm v-pass + LINEAR bf16 W copy ---------------
__global__ __launch_bounds__(512) void k_sn_v(
    const float* __restrict__ hqW, const float* __restrict__ hkW,
    const float* __restrict__ uq, const float* __restrict__ uk,
    float* __restrict__ vpart, ushort* __restrict__ Wbf){
  __shared__ float red[8*520];
  int z = blockIdx.y; int k = z >> 1, qk = z & 1;
  const float* W = (qk ? hkW : hqW) + (long)k*WROWS*DMD;
  const float* u = (qk ? uk : uq) + (long)k*WROWS;
  ushort* Wb = Wbf ? (Wbf + (long)z*WROWS*DMD) : nullptr;
  int t = threadIdx.x;
  int c8 = (t & 63) * 8;
  int rsub = t >> 6;
  int r0 = blockIdx.x * 256;
  float acc[8] = {};
  for (int r = rsub; r < 256; r += 16){
    int ra = r0 + r, rb = r0 + r + 8;
    long offa = (long)ra*DMD + c8, offb = (long)rb*DMD + c8;
    f32x4 a0 = __builtin_nontemporal_load((const f32x4*)(W + offa));
    f32x4 a1 = __builtin_nontemporal_load((const f32x4*)(W + offa + 4));
    f32x4 b0 = __builtin_nontemporal_load((const f32x4*)(W + offb));
    f32x4 b1 = __builtin_nontemporal_load((const f32x4*)(W + offb + 4));
    float ua = u[ra], ub = u[rb];
    float av[8] = {a0[0],a0[1],a0[2],a0[3],a1[0],a1[1],a1[2],a1[3]};
    float bv[8] = {b0[0],b0[1],b0[2],b0[3],b1[0],b1[1],b1[2],b1[3]};
    #pragma unroll
    for (int i = 0; i < 8; i++) acc[i] += av[i]*ua + bv[i]*ub;
    if (Wb){
      short8v oa, ob;
      #pragma unroll
      for (int i = 0; i < 8; i++){ oa[i] = (short)f2bf(av[i]); ob[i] = (short)f2bf(bv[i]); }
      __builtin_nontemporal_store(oa, (short8v*)(Wb + offa));
      __builtin_nontemporal_store(ob, (short8v*)(Wb + offb));
    }
  }
  #pragma unroll
  for (int i = 0; i < 8; i++) red[rsub*520 + c8 + i] = acc[i];
  __syncthreads();
  if (rsub == 0){
    #pragma unroll
    for (int i = 0; i < 8; i++){
      int c = c8 + i;
      float s = 0.f;
      #pragma unroll
      for (int w = 0; w < 8; w++) s += red[w*520 + c];
      vpart[((long)z*128 + blockIdx.x)*512 + c] = s;
    }
  }
}

// reduce vpart -> normalized v; write qpb row4 = v-hat, zero rows 5..63
__global__ __launch_bounds__(512) void k_sn_norm(const float* __restrict__ vpart,
                                                 float* __restrict__ vraw,
                                                 ushort* __restrict__ qpb){
  __shared__ float red[512];
  int z = blockIdx.x; int t = threadIdx.x;
  float s = 0.f;
  for (int c = 0; c < 128; c++) s += vpart[((long)z*128 + c)*512 + t];
  red[t] = s*s; __syncthreads();
  for (int o = 256; o; o >>= 1){
    if (t < o) red[t] += red[t+o];
    __syncthreads();
  }
  float nrm = sqrtf(red[0]);
  float v = s / (nrm + 1e-12f);
  vraw[z*512 + t] = v;
  ushort* p = qpb + (long)z*32768;
  p[4*512 + t] = f2bf(v);
  for (int r = 5; r < 64; r++) p[r*512 + t] = 0;
}

// f32 fallback sigma pass
__global__ void k_sn_s(const float* __restrict__ hqW, const float* __restrict__ hkW,
                       const float* __restrict__ vraw, float* __restrict__ ssqp){
  int z = blockIdx.y; int k = z >> 1, qk = z & 1;
  const float* W = (qk ? hkW : hqW) + (long)k*WROWS*DMD;
  const float* v = vraw + z*DMD;
  int wave = threadIdx.x >> 6, lane = threadIdx.x & 63;
  float vreg[8];
  #pragma unroll
  for (int i = 0; i < 8; i++) vreg[i] = v[lane + 64*i];
  int r0 = blockIdx.x*256 + wave*64;
  float acc = 0.f;
  for (int r = r0; r < r0+64; r++){
    float p = 0.f;
    #pragma unroll
    for (int i = 0; i < 8; i++)
      p += W[(long)r*DMD + lane + 64*i] * vreg[i];
    for (int off = 32; off; off >>= 1) p += __shfl_down(p, off);
    if (lane == 0) acc += p*p;
  }
  if (lane == 0) atomicAdd(&ssqp[z*64 + (blockIdx.x & 63)], acc);
}

// f32 fallback proj
__global__ void k_proj(const float* __restrict__ hqW, const float* __restrict__ hkW,
                       const float* __restrict__ qp,
                       ushort* __restrict__ OqT, ushort* __restrict__ OkT, int k){
  int z = blockIdx.y;
  const float* W = (z ? hkW : hqW) + (long)k*WROWS*DMD;
  ushort* O = z ? OkT : OqT;
  int wave = threadIdx.x >> 6, lane = threadIdx.x & 63;
  long r = (long)blockIdx.x*4 + wave;
  float a0=0,a1=0,a2=0,a3=0;
  for (int j = lane; j < DMD; j += 64){
    float w = W[r*DMD + j];
    a0 += w*qp[j]; a1 += w*qp[DMD+j]; a2 += w*qp[2*DMD+j]; a3 += w*qp[3*DMD+j];
  }
  for (int off = 32; off; off >>= 1){
    a0 += __shfl_down(a0,off); a1 += __shfl_down(a1,off);
    a2 += __shfl_down(a2,off); a3 += __shfl_down(a3,off);
  }
  if (lane == 0){
    int d = (int)(r >> 6), e = (int)(r & 63);
    long o = (long)e*512 + d;
    O[o] = f2bf(a0); O[32768+o] = f2bf(a1);
    O[2*32768+o] = f2bf(a2); O[3*32768+o] = f2bf(a3);
  }
}

// ---------------- bf16 MFMA GEMM: C = A . B^T (+epilogue), BK=64 ----------
// EPI: 0 none | 1 elu(acc*invsigma+bias[col])+1 | 3 res+sp*(acc+bias[col])
//      | 4 acc+res (+aux store) | 6 proj (rows<4 bf16; row4 -> ssq atomic)
// CVTB: B operand is f32 global, converted during staging.
// TRN: tm from blockIdx.x, tn from blockIdx.y (B-panel L2 reuse).
// PERM: B tile row p gathers original row (p&511)*64 + (p>>9).
// NTC: non-temporal C stores.
template<int BM, int BN, int WM, int WN, int EPI, int BFOUT, int DUAL, int RSUM,
         int CVTB = 0, int TRN = 0, int PERM = 0, int NTC = 0>
__global__ __launch_bounds__(256) void mm_bt(
    const ushort* __restrict__ A, const ushort* __restrict__ B, void* __restrict__ C,
    int N, int K, long sA, long sB, long sC,
    const float* __restrict__ bias, const float* __restrict__ bias2,
    const float* __restrict__ res, const ushort* __restrict__ resb,
    const float* __restrict__ dtp, int dtidx,
    float* __restrict__ aux, const float* __restrict__ ssqp)
{
  __shared__ ushort As[BM*64];
  __shared__ ushort Bs[BN*64];
  const int z = blockIdx.z;
  const float* biasz = bias;
  if (DUAL){
    A += (long)(z & 3)*sA;
    if (z >= 4) biasz = bias2;
  } else {
    A += (long)z*sA;
  }
  if (!CVTB) B += (long)z*sB;
  const int tm = (TRN ? blockIdx.x : blockIdx.y)*BM;
  const int tn = DUAL ? 0 : (TRN ? blockIdx.y : blockIdx.x)*BN;
  const int tid = threadIdx.x;
  const int wid = tid >> 6, lane = tid & 63;
  constexpr int NWN = BN/WN;
  const int wr = wid / NWN, wc = wid % NWN;
  constexpr int FM = WM/16, FN = WN/16;
  const int ln15 = lane & 15, kq = lane >> 4;
  constexpr int LA = BM/32;
  constexpr int LB = BN/32;
  f32x4 acc[FM][FN] = {};

  for (int k0 = 0; k0 < K; k0 += 64){
    #pragma unroll
    for (int l = 0; l < LA; l++){
      int slot = tid + l*256;
      int row = slot >> 3, ch = slot & 7;
      int gch = ch ^ (row & 7);
      const char* g = (const char*)(A + (long)(tm+row)*K + k0) + gch*16;
      ushort* lp = As + (size_t)(wid*64 + l*256)*8;
      __builtin_amdgcn_global_load_lds((const __attribute__((address_space(1))) void*)g,
                                       (__attribute__((address_space(3))) void*)lp, 16, 0, 0);
    }
    #pragma unroll
    for (int l = 0; l < LB; l++){
      int slot = tid + l*256;
      int row = slot >> 3, ch = slot & 7;
      int gch = ch ^ (row & 7);
      if (CVTB){
        const float* Bf = (const float*)B;
        const float* src = Bf + (long)(tn+row)*K + k0 + gch*8;
        float4 v0 = *(const float4*)src;
        float4 v1 = *(const float4*)(src + 4);
        float vv[8] = {v0.x,v0.y,v0.z,v0.w,v1.x,v1.y,v1.z,v1.w};
        short8v o;
        #pragma unroll
        for (int i = 0; i < 8; i++) o[i] = (short)f2bf(vv[i]);
        *(short8v*)&Bs[(size_t)slot*8] = o;
      } else {
        long brow;
        if (PERM){
          int p = tn + row;
          brow = (long)((p & 511)*64 + (p >> 9));
        } else {
          brow = (long)(tn + row);
        }
        const char* g = (const char*)(B + brow*K + k0) + gch*16;
        ushort* lp = Bs + (size_t)(wid*64 + l*256)*8;
        __builtin_amdgcn_global_load_lds((const __attribute__((address_space(1))) void*)g,
                                         (__attribute__((address_space(3))) void*)lp, 16, 0, 0);
      }
    }
    __syncthreads();
    #pragma unroll
    for (int ks = 0; ks < 2; ks++){
      short8v af[FM], bfr[FN];
      #pragma unroll
      for (int i = 0; i < FM; i++){
        int row = wr*WM + i*16 + ln15;
        af[i] = *(const short8v*)&As[row*64 + (((ks*4+kq) ^ (row&7))*8)];
      }
      #pragma unroll
      for (int j = 0; j < FN; j++){
        int row = wc*WN + j*16 + ln15;
        bfr[j] = *(const short8v*)&Bs[row*64 + (((ks*4+kq) ^ (row&7))*8)];
      }
      #pragma unroll
      for (int i = 0; i < FM; i++)
        #pragma unroll
        for (int j = 0; j < FN; j++)
          acc[i][j] = __builtin_amdgcn_mfma_f32_16x16x32_bf16(af[i], bfr[j], acc[i][j], 0, 0, 0);
    }
    __syncthreads();
  }

  float sp = 0.f, invs = 1.f;
  if (EPI == 3) sp = log1pf(expf(dtp[dtidx]));
  if (EPI == 1){
    const float* sq = ssqp + (DUAL ? (z >> 2)*64 : 0);
    float s2 = 0.f;
    for (int i = 0; i < 64; i++) s2 += sq[i];
    invs = (sqrtf(s2) + 1e-12f) / s2;
  }
  float* Cf = (float*)C + (long)z*sC;
  ushort* Cb = (ushort*)C + (long)z*sC;
  const float* rz = res ? (res + (long)z*sC) : nullptr;
  float sacc = 0.f;
  #pragma unroll
  for (int i = 0; i < FM; i++){
    int row0 = tm + wr*WM + i*16 + kq*4;
    #pragma unroll
    for (int j = 0; j < FN; j++){
      int col = tn + wc*WN + j*16 + ln15;
      #pragma unroll
      for (int r = 0; r < 4; r++){
        int row = row0 + r;
        long idx = (long)row*N + col;
        float v = acc[i][j][r];
        if (EPI == 6){
          if (row < 4) Cb[idx] = f2bf(v);
          else if (row == 4) sacc += v*v;
          continue;
        }
        if (EPI == 1){ v = v*invs + biasz[col]; v = v > 0.f ? v : expm1f(v); v += 1.f; }
        else if (EPI == 3){ v = rz[idx] + sp*(v + biasz[col]); }
        else if (EPI == 4){ v = v + rz[idx]; if (aux) aux[idx] = v; }
        if (BFOUT) Cb[idx] = f2bf(v);
        else if (NTC) __builtin_nontemporal_store(v, &Cf[idx]);
        else       Cf[idx] = v;
      }
    }
  }
  if (EPI == 6 && aux){
    sacc += __shfl_xor(sacc, 1); sacc += __shfl_xor(sacc, 2);
    sacc += __shfl_xor(sacc, 4); sacc += __shfl_xor(sacc, 8);
    if (wr == 0 && kq == 1 && ln15 == 0)
      atomicAdd(&aux[(long)z*64 + ((int)blockIdx.x & 63)], sacc);
  }
}

// ---------------- fused attention: S=Pq.Pk^T -> relu^2 -> rowsum + @Qn ----
__global__ __launch_bounds__(256) void k_attn(
    const ushort* __restrict__ Pqk, const ushort* __restrict__ QnT,
    const ushort* __restrict__ Qn, ushort* __restrict__ m_out)
{
  __shared__ ushort Aq[64*64];
  __shared__ ushort Bk[64*64];
  __shared__ ushort Qs[64*64];
  __shared__ ushort Ws[64*72];
  __shared__ float nrmL[2][64];
  const int cg = blockIdx.x, nt = blockIdx.y, b = blockIdx.z;
  const int tid = threadIdx.x, wid = tid >> 6;
  const int lane = tid & 63, ln15 = lane & 15, kq = lane >> 4;
  const int wr = wid >> 1, wc = wid & 1;
  const ushort* Pq  = Pqk + (long)b*32768 + (long)nt*4096;
  const ushort* Pk0 = Pqk + 131072 + (long)b*32768;
  const ushort* Qt  = QnT + (long)b*262144 + (long)(cg*64)*512;

  #pragma unroll
  for (int l = 0; l < 2; l++){
    int slot = tid + l*256;
    int row = slot >> 3, gch = (slot & 7) ^ (row & 7);
    __builtin_amdgcn_global_load_lds(
        (const __attribute__((address_space(1))) void*)((const char*)(Pq + (long)row*64) + gch*16),
        (__attribute__((address_space(3))) void*)(Aq + (size_t)(wid*64 + l*256)*8), 16, 0, 0);
  }
  f32x4 acc[2][2] = {};
  float nacc[2][4] = {};
  for (int mt = 0; mt < 8; mt++){
    #pragma unroll
    for (int l = 0; l < 2; l++){
      int slot = tid + l*256;
      int row = slot >> 3, gch = (slot & 7) ^ (row & 7);
      __builtin_amdgcn_global_load_lds(
          (const __attribute__((address_space(1))) void*)((const char*)(Pk0 + (long)mt*4096 + (long)row*64) + gch*16),
          (__attribute__((address_space(3))) void*)(Bk + (size_t)(wid*64 + l*256)*8), 16, 0, 0);
      __builtin_amdgcn_global_load_lds(
          (const __attribute__((address_space(1))) void*)((const char*)(Qt + (long)row*512 + mt*64) + gch*16),
          (__attribute__((address_space(3))) void*)(Qs + (size_t)(wid*64 + l*256)*8), 16, 0, 0);
    }
    __syncthreads();
    f32x4 sA[2][2] = {};
    #pragma unroll
    for (int ks = 0; ks < 2; ks++){
      short8v af[2], bfr[2];
      #pragma unroll
      for (int i = 0; i < 2; i++){
        int row = wr*32 + i*16 + ln15;
        af[i] = *(const short8v*)&Aq[row*64 + (((ks*4+kq) ^ (row&7))*8)];
      }
      #pragma unroll
      for (int j = 0; j < 2; j++){
        int row = wc*32 + j*16 + ln15;
        bfr[j] = *(const short8v*)&Bk[row*64 + (((ks*4+kq) ^ (row&7))*8)];
      }
      #pragma unroll
      for (int i = 0; i < 2; i++)
        #pragma unroll
        for (int j = 0; j < 2; j++)
          sA[i][j] = __builtin_amdgcn_mfma_f32_16x16x32_bf16(af[i], bfr[j], sA[i][j], 0, 0, 0);
    }
    float t[2][4] = {};
    #pragma unroll
    for (int i = 0; i < 2; i++)
      #pragma unroll
      for (int j = 0; j < 2; j++)
        #pragma unroll
        for (int r = 0; r < 4; r++){
          float v = fmaxf(sA[i][j][r], 0.f); v = v*v;
          t[i][r] += v;
          int row = wr*32 + i*16 + kq*4 + r;
          int col = wc*32 + j*16 + ln15;
          Ws[row*72 + col] = f2bf(v);
        }
    #pragma unroll
    for (int i = 0; i < 2; i++)
      #pragma unroll
      for (int r = 0; r < 4; r++){
        float x = t[i][r];
        x += __shfl_xor(x, 1); x += __shfl_xor(x, 2);
        x += __shfl_xor(x, 4); x += __shfl_xor(x, 8);
        nacc[i][r] += x;
      }
    __syncthreads();
    #pragma unroll
    for (int ks = 0; ks < 2; ks++){
      short8v af[2], bfr[2];
      #pragma unroll
      for (int i = 0; i < 2; i++){
        int row = wr*32 + i*16 + ln15;
        af[i] = *(const short8v*)&Ws[row*72 + (ks*4+kq)*8];
      }
      #pragma unroll
      for (int j = 0; j < 2; j++){
        int row = wc*32 + j*16 + ln15;
        bfr[j] = *(const short8v*)&Qs[row*64 + (((ks*4+kq) ^ (row&7))*8)];
      }
      #pragma unroll
      for (int i = 0; i < 2; i++)
        #pragma unroll
        for (int j = 0; j < 2; j++)
          acc[i][j] = __builtin_amdgcn_mfma_f32_16x16x32_bf16(af[i], bfr[j], acc[i][j], 0, 0, 0);
    }
    __syncthreads();
  }
  if (ln15 == 0){
    #pragma unroll
    for (int i = 0; i < 2; i++)
      #pragma unroll
      for (int r = 0; r < 4; r++)
        nrmL[wc][wr*32 + i*16 + kq*4 + r] = nacc[i][r];
  }
  __syncthreads();
  #pragma unroll
  for (int i = 0; i < 2; i++){
    #pragma unroll
    for (int r = 0; r < 4; r++){
      int rowl = wr*32 + i*16 + kq*4 + r;
      float Nr = fabsf(nrmL[0][rowl] + nrmL[1][rowl]) + 1.f;
      int n = nt*64 + rowl;
      #pragma unroll
      for (int j = 0; j < 2; j++){
        int col = cg*64 + wc*32 + j*16 + ln15;
        long idx = (long)b*262144 + (long)n*512 + col;
        m_out[idx] = f2bf(acc[i][j][r]/Nr - bf2f(Qn[idx]));
      }
    }
  }
}

// ---------------- small kernels ----------------
__global__ void k_qp2(const float* __restrict__ part, float* __restrict__ qp,
                      ushort* __restrict__ qpb){
  int b = blockIdx.x, t = threadIdx.x;
  float s = 0.f;
  #pragma unroll
  for (int c = 0; c < 32; c++) s += part[((long)b*32 + c)*512 + t];
  float val = s * (1.f/512.f);
  qp[b*512 + t] = val;
  ushort bv = f2bf(val);
  #pragma unroll
  for (int z = 0; z < 8; z++)
    qpb[(long)z*32768 + (long)b*512 + t] = bv;
}

__global__ void k_convfuse(const ushort* __restrict__ GU, const float* __restrict__ w,
                           ushort* __restrict__ Hc){
  int r = blockIdx.x;
  int n = r & 511;
  int c = threadIdx.x * 8;
  long base = (long)r*4096 + c;
  float o[8] = {};
  if (n > 0){
    short8v gv = *(const short8v*)&GU[base-4096];
    short8v uv = *(const short8v*)&GU[base-4096+2048];
    #pragma unroll
    for (int i = 0; i < 8; i++){
      float g = bf2f((ushort)gv[i]), u = bf2f((ushort)uv[i]);
      o[i] += g/(1.f+expf(-g))*u * w[(c+i)*3+0];
    }
  }
  {
    short8v gv = *(const short8v*)&GU[base];
    short8v uv = *(const short8v*)&GU[base+2048];
    #pragma unroll
    for (int i = 0; i < 8; i++){
      float g = bf2f((ushort)gv[i]), u = bf2f((ushort)uv[i]);
      o[i] += g/(1.f+expf(-g))*u * w[(c+i)*3+1];
    }
  }
  if (n < 511){
    short8v gv = *(const short8v*)&GU[base+4096];
    short8v uv = *(const short8v*)&GU[base+4096+2048];
    #pragma unroll
    for (int i = 0; i < 8; i++){
      float g = bf2f((ushort)gv[i]), u = bf2f((ushort)uv[i]);
      o[i] += g/(1.f+expf(-g))*u * w[(c+i)*3+2];
    }
  }
  short8v ov;
  #pragma unroll
  for (int i = 0; i < 8; i++) ov[i] = (short)f2bf(o[i]);
  *(short8v*)&Hc[(long)r*2048 + c] = ov;
}

__global__ void k_cvt3(const float* __restrict__ s0, ushort* __restrict__ d0, long n0,
                       const float* __restrict__ s1, ushort* __restrict__ d1, long n1,
                       const float* __restrict__ s2, ushort* __restrict__ d2, long n2){
  long i = ((long)blockIdx.x*256 + threadIdx.x)*4;
  const float* s; ushort* d; long off;
  if (i < n0){ s = s0; d = d0; off = i; }
  else if (i < n0 + n1){ s = s1; d = d1; off = i - n0; }
  else { s = s2; d = d2; off = i - n0 - n1; }
  float4 v = *(const float4*)(s + off);
  ushort4 o;
  o.x = f2bf(v.x); o.y = f2bf(v.y); o.z = f2bf(v.z); o.w = f2bf(v.w);
  *(ushort4*)(d + off) = o;
}

__global__ void k_cvt(const float* __restrict__ in, ushort* __restrict__ out){
  long i = ((long)blockIdx.x*256 + threadIdx.x)*4;
  f32x4 v = __builtin_nontemporal_load((const f32x4*)(in + i));
  ushort4 o;
  o.x = f2bf(v[0]); o.y = f2bf(v[1]); o.z = f2bf(v[2]); o.w = f2bf(v[3]);
  *(ushort4*)(out + i) = o;
}

__global__ void k_fin(const int* __restrict__ halted32, const int* __restrict__ steps,
                      const float* __restrict__ hpart, const float* __restrict__ hb,
                      float* __restrict__ o_halt, float* __restrict__ o_steps,
                      float* __restrict__ o_halted){
  int t = threadIdx.x;
  if (t < NBATCH){
    o_halt[t] = hpart[t]*(1.f/512.f) + hb[0];
    bool hall = (halted32[0] != 0);
    int ns = (hall ? 0 : steps[t]) + 1;
    o_steps[t] = (float)ns;
    o_halted[t] = ns >= 6 ? 1.f : 0.f;
  }
}

// ---------------- launch ----------------
extern "C" void kernel_launch(void* const* d_in, const int* in_sizes, int n_in,
                              void* d_out, int out_size, void* d_ws, size_t ws_size,
                              hipStream_t stream)
{
  const int*     inputs       = (const int*)d_in[0];
  const int*     halted32     = (const int*)d_in[2];
  const int*     steps        = (const int*)d_in[3];
  const float*   carry_hidden = (const float*)d_in[4];
  const int*     carry_inputs = (const int*)d_in[5];
  const float*   embedding    = (const float*)d_in[7];
  const float*   pos_emb      = (const float*)d_in[8];
  const float*   in_g = (const float*)d_in[9];
  const float*   in_b = (const float*)d_in[10];
  const float*   init_hidden = (const float*)d_in[11];
  const float*   dt   = (const float*)d_in[12];
  const float*   mW   = (const float*)d_in[13];
  const float*   mb   = (const float*)d_in[14];
  const float*   hqW  = (const float*)d_in[15];
  const float*   hkW  = (const float*)d_in[16];
  const float*   uq   = (const float*)d_in[17];
  const float*   uk   = (const float*)d_in[18];
  const float*   BQb  = (const float*)d_in[19];
  const float*   BKb  = (const float*)d_in[20];
  const float*   g1   = (const float*)d_in[21];
  const float*   b1   = (const float*)d_in[22];
  const float*   g2   = (const float*)d_in[23];
  const float*   b2   = (const float*)d_in[24];
  const float*   WupW = (const float*)d_in[25];
  const float*   convW= (const float*)d_in[26];
  const float*   WdownW=(const float*)d_in[27];
  const float*   fin_g= (const float*)d_in[28];
  const float*   fin_b= (const float*)d_in[29];
  const float*   halt_W=(const float*)d_in[30];
  const float*   halt_b=(const float*)d_in[31];
  const float*   lm_head=(const float*)d_in[32];
  float* out = (float*)d_out;

  float* ws = (float*)d_ws;
  float*  X    = ws;
  float*  Qa   = ws +  1048576;
  float*  Qb   = ws +  2097152;
  ushort* qpb  = (ushort*)(ws + 3145728);      // 8 x 64 x 512 bf16
  float*  vpart  = ws + 3276800;               // 8 x 128 x 512 f32 (prologue only)
  float*  qp_part= ws + 3801088;               // 4 x 32 x 512 f32
  ushort* GU_bf  = (ushort*)(ws +  4194304);   // 8,388,608 elems
  ushort* Hc_bf  = (ushort*)(ws +  8388608);   // 4,194,304 elems
  ushort* m_bf   = (ushort*)(ws + 10485760);   // 1,048,576 elems
  ushort* QnT_bf = (ushort*)(ws + 11534336);   // 1,048,576 elems
  ushort* Pq_bf  = (ushort*)(ws + 12058624);   // 131,072 (Pk contiguous after)
  ushort* OqT    = (ushort*)(ws + 12189696);   // 131,072 (OkT contiguous after)
  ushort* lm_bf  = (ushort*)(ws +  4194304);   // post-loop overlay (16.38M ushorts,
                                               // ends at slot 12386304 < Qn_bf)
  ushort* Qn_bf  = (ushort*)(ws + 13369344);   // 1,048,576 elems
  ushort* mW_bf  = (ushort*)(ws + 13893632);
  ushort* Wup_bf = (ushort*)(ws + 14417920);
  ushort* Wdn_bf = (ushort*)(ws + 18612224);
  float*  qp       = ws + 20709376;  // 2048
  float*  vraw     = ws + 20713472;  // 4096
  float*  ssq_part = ws + 20717568;  // 512  -- zero region start
  float*  hpart    = ws + 20718080;  // 64   -- zero region end (576 total)
  ushort* W_bf = (ushort*)(ws + 20750976);
  const size_t NEED_BF = (size_t)(20750976 + 67108864) * 4;
  const bool useBf = ws_size >= NEED_BF;

  k_cvt3<<<13312, 256, 0, stream>>>(mW, mW_bf, 1048576L,
                                    WupW, Wup_bf, 8388608L,
                                    WdownW, Wdn_bf, 4194304L);

  hipMemsetAsync(ssq_part, 0, 576*sizeof(float), stream);
  k_sn_v<<<dim3(128,8), 512, 0, stream>>>(hqW, hkW, uq, uk, vpart,
                                          useBf ? W_bf : nullptr);
  k_sn_norm<<<8, 512, 0, stream>>>(vpart, vraw, qpb);
  if (!useBf)
    k_sn_s<<<dim3(128,8), 256, 0, stream>>>(hqW, hkW, vraw, ssq_part);

  k_embed_ln<<<2048, 256, 0, stream>>>(inputs, carry_inputs, halted32,
                                       embedding, pos_emb, in_g, in_b, X);

  for (int cyc = 0; cyc < 2; cyc++){
    for (int k = 0; k < 4; k++){
      if (k == 0){
        if (cyc == 0)
          k_ln1<1,1,1,0><<<dim3(32,4), 512, 0, stream>>>(
              Qa, Qa, X, halted32, init_hidden, carry_hidden,
              Qn_bf, QnT_bf, qp_part, g1 + k*DMD, b1 + k*DMD, nullptr, nullptr);
        else
          k_ln1<2,1,1,0><<<dim3(32,4), 512, 0, stream>>>(
              Qa, Qa, X, nullptr, nullptr, nullptr,
              Qn_bf, QnT_bf, qp_part, g1 + k*DMD, b1 + k*DMD, nullptr, nullptr);
      } else {
        k_ln1<0,1,1,0><<<dim3(32,4), 512, 0, stream>>>(
            Qa, nullptr, nullptr, nullptr, nullptr, nullptr,
            Qn_bf, QnT_bf, qp_part, g1 + k*DMD, b1 + k*DMD, nullptr, nullptr);
      }
      k_qp2<<<4, 512, 0, stream>>>(qp_part, qp, qpb);
      // O(q|k) = qp @ W^T; W_bf linear, permutation applied on read (PERM=1)
      if (useBf)
        mm_bt<64,64,32,32,6,1,0,1,0,0,1><<<dim3(512,1,2), 256, 0, stream>>>(
            qpb + (long)k*2*32768, W_bf + (long)k*2*16777216, OqT,
            32768, 512, 32768, 16777216, 131072,
            nullptr, nullptr, nullptr, nullptr, nullptr, 0,
            (cyc == 0) ? (ssq_part + k*128) : nullptr, nullptr);
      else
        k_proj<<<dim3(8192,2), 256, 0, stream>>>(hqW, hkW, qp, OqT, OqT + 131072, k);
      // Pq|Pk = elu((Qn @ O)/sigma + bias)+1
      mm_bt<64,64,32,32,1,1,1,0><<<dim3(1,8,8), 256, 0, stream>>>(
          Qn_bf, OqT, Pq_bf, 64, 512, 262144, 32768, 32768,
          BQb + k*64, BKb + k*64, nullptr, nullptr, nullptr, 0,
          nullptr, ssq_part + k*128);
      // fused attention: Wm + rowsum + Att + (/Nrm - Qn) -> m_bf
      k_attn<<<dim3(8,8,4), 256, 0, stream>>>(Pq_bf, QnT_bf, Qn_bf, m_bf);
      // Qi = Qa + softplus(dt)*(m @ mW^T + mb) -> Qb (f32), 64x64 tile
      mm_bt<64,64,32,32,3,0,0,0><<<dim3(8,32,1), 256, 0, stream>>>(
          m_bf, mW_bf + (long)k*262144, Qb, 512, 512, 0, 0, 0,
          mb + k*DMD, nullptr, Qa, nullptr, dt, k, nullptr, nullptr);
      // LN2 -> Qn_bf only
      k_ln1<0,0,0,0><<<dim3(32,4), 512, 0, stream>>>(
          Qb, nullptr, nullptr, nullptr, nullptr, nullptr,
          Qn_bf, nullptr, nullptr, g2 + k*DMD, b2 + k*DMD, nullptr, nullptr);
      // GU = Qn2 @ WupW^T (bf16 out), TRN grid for B-panel L2 reuse
      mm_bt<128,128,64,64,0,1,0,0,0,1><<<dim3(16,32,1), 256, 0, stream>>>(
          Qn_bf, Wup_bf + (long)k*2097152, GU_bf, 4096, 512, 0, 0, 0,
          nullptr, nullptr, nullptr, nullptr, nullptr, 0, nullptr, nullptr);
      k_convfuse<<<2048, 256, 0, stream>>>(GU_bf, convW + (long)k*2048*3, Hc_bf);
      // Q_next = Qi + Hc @ WdownW^T -> Qa (f32), 64x64 tile; last iter also -> out
      float* aux = (cyc == 1 && k == 3) ? (out + OFF_Q) : nullptr;
      mm_bt<64,64,32,32,4,0,0,0><<<dim3(8,32,1), 256, 0, stream>>>(
          Hc_bf, Wdn_bf + (long)k*1048576, Qa, 512, 2048, 0, 0, 0,
          nullptr, nullptr, Qb, nullptr, nullptr, 0, aux, nullptr);
    }
  }

  // final LN (+halt dot); convert lm_head -> bf16 (overlay); lm GEMM with
  // bf16 B (half the panel traffic), TRN grid, NTC logits stores.
  k_ln1<0,0,0,1><<<dim3(32,4), 512, 0, stream>>>(
      Qa, nullptr, nullptr, nullptr, nullptr, nullptr,
      Qn_bf, nullptr, nullptr, fin_g, fin_b, halt_W, hpart);
  k_cvt<<<16000, 256, 0, stream>>>(lm_head, lm_bf);
  mm_bt<128,128,64,64,0,0,0,0,0,1,0,1><<<dim3(16,250,1), 256, 0, stream>>>(
      Qn_bf, lm_bf, out, 32000, 512, 0, 0, 0,
      nullptr, nullptr, nullptr, nullptr, nullptr, 0, nullptr, nullptr);
  k_fin<<<1, 64, 0, stream>>>(halted32, steps, hpart, halt_b,
                              out + OFF_HALT, out + OFF_STEPS, out + OFF_HALTED);
}